// Round 27
// baseline (178.421 us; speedup 1.0000x reference)
//
#include <hip/hip_runtime.h>
#include <hip/hip_bf16.h>

#define DMODEL 1024
#define DI     2048
#define DSTATE 128
#define NH     32
#define HD     64
#define CONVD  2304
#define LSEQ   2048
#define BATCH  2
#define DPROJ  4384
#define NPAD   4480      // zxb column stride
#define EPSV   1e-5f
#define QCH    128
#define NCH    16

#define AS1 __attribute__((address_space(1)))
#define AS3 __attribute__((address_space(3)))

typedef __attribute__((ext_vector_type(8))) short bf16x8;
typedef __attribute__((ext_vector_type(4))) float f32x4;

union U4 { ushort4 u; __hip_bfloat16 h[4]; };

__device__ __forceinline__ float bf2f(unsigned short u) {
  union { unsigned int i; float f; } c; c.i = ((unsigned)u) << 16; return c.f;
}
__device__ __forceinline__ ushort4 pack4(float x0, float x1, float x2, float x3) {
  U4 p;
  p.h[0] = __float2bfloat16(x0); p.h[1] = __float2bfloat16(x1);
  p.h[2] = __float2bfloat16(x2); p.h[3] = __float2bfloat16(x3);
  return p.u;
}

// ---- swizzled LDS helpers: [rows][128] bf16 tiles (256B rows), byte ^= (row&7)<<4 ----
__device__ __forceinline__ bf16x8 ldsfrag(const __hip_bfloat16* base, int row, int ke) {
  int byte = row * 256 + ke * 2;
  byte ^= (row & 7) << 4;
  return *reinterpret_cast<const bf16x8*>(reinterpret_cast<const char*>(base) + byte);
}
__device__ __forceinline__ void ldswr4(__hip_bfloat16* base, int row, int col, ushort4 v) {
  int byte = row * 256 + col * 2;
  byte ^= (row & 7) << 4;
  *reinterpret_cast<ushort4*>(reinterpret_cast<char*>(base) + byte) = v;
}
__device__ __forceinline__ ushort4 ldsrd4(const __hip_bfloat16* base, int row, int col) {
  int byte = row * 256 + col * 2;
  byte ^= (row & 7) << 4;
  return *reinterpret_cast<const ushort4*>(reinterpret_cast<const char*>(base) + byte);
}
__device__ __forceinline__ void ldswr8(__hip_bfloat16* base, int row, int colElem,
                                       unsigned lo, unsigned hi) {
  int byte = row * 256 + colElem * 2;
  byte ^= (row & 7) << 4;
  uint2 v; v.x = lo; v.y = hi;
  *reinterpret_cast<uint2*>(reinterpret_cast<char*>(base) + byte) = v;
}
// ---- swizzled helper for [rows][32] bf16 tiles (64B rows): chunk g ^= (row>>1)&3 ----
__device__ __forceinline__ bf16x8 frag32(const __hip_bfloat16* base, int row, int g) {
  int byte = row * 64 + (((g ^ (row >> 1)) & 3) << 4);
  return *reinterpret_cast<const bf16x8*>(reinterpret_cast<const char*>(base) + byte);
}

// ---- in-register 4x4 u16 transpose across a quad (lanes ql=0..3) ----
__device__ __forceinline__ void quadtr(unsigned a01, unsigned a23, int ql,
                                       unsigned& w01, unsigned& w23) {
  unsigned y01 = __shfl_xor((int)a01, 1), y23 = __shfl_xor((int)a23, 1);
  unsigned c01 = (ql & 1) ? ((y01 >> 16) | (a01 & 0xFFFF0000u))
                          : ((a01 & 0xFFFFu) | (y01 << 16));
  unsigned c23 = (ql & 1) ? ((y23 >> 16) | (a23 & 0xFFFF0000u))
                          : ((a23 & 0xFFFFu) | (y23 << 16));
  unsigned d01 = __shfl_xor((int)c01, 2), d23 = __shfl_xor((int)c23, 2);
  w01 = (ql & 2) ? d23 : c01;
  w23 = (ql & 2) ? c23 : d01;
}

// ---------------- merged prep: x->bf16 + W_in^T + W_out^T in one launch ----------------

__global__ __launch_bounds__(256)
void prep_kernel(const float* __restrict__ x, __hip_bfloat16* __restrict__ xbf,
                 const float* __restrict__ W_in, __hip_bfloat16* __restrict__ wtin,
                 const float* __restrict__ W_out, __hip_bfloat16* __restrict__ wtout) {
  __shared__ float tile[32][33];
  const int b = blockIdx.x, tid = threadIdx.x;
  if (b < 4096) {
    int i = b * 256 + tid;
    float4 v = reinterpret_cast<const float4*>(x)[i];
    reinterpret_cast<ushort4*>(xbf)[i] = pack4(v.x, v.y, v.z, v.w);
    return;
  }
  const float* in;
  __hip_bfloat16* outp;
  int R, C, Cpad, n0, k0;
  if (b < 4096 + 4480) {
    int t = b - 4096;
    in = W_in; outp = wtin; R = 1024; C = 4384; Cpad = 4480;
    n0 = (t % 140) * 32; k0 = (t / 140) * 32;
  } else {
    int t = b - 8576;
    in = W_out; outp = wtout; R = 2048; C = 1024; Cpad = 1024;
    n0 = (t % 32) * 32; k0 = (t / 32) * 32;
  }
  int tx = tid & 31, ty = tid >> 5;
#pragma unroll
  for (int j = 0; j < 32; j += 8) {
    int k = k0 + ty + j, n = n0 + tx;
    tile[ty + j][tx] = (n < C) ? in[(size_t)k * C + n] : 0.f;
  }
  __syncthreads();
#pragma unroll
  for (int j = 0; j < 32; j += 8) {
    int n = n0 + ty + j, k = k0 + tx;
    if (n < Cpad) outp[(size_t)n * R + k] = __float2bfloat16(tile[tx][ty + j]);
  }
}

// ---------------- GEMM 256x256: BK=32, 4-buffer depth-2 counted-vmcnt ----------------
// MODE 0: GEMM1 — grid 256; block (p=bm/256, q=bn/256) computes its 256^2 main tile
//         AND the remainder tile {rows p*256+(q&1)*128..+128, cols 4096+(q>>1)*48..+48}
//         FUSED into the same K-pipeline (B2 staged by waves 0-2). +dt side-channel.
//         Epilogue: quadtr-transposed ushort4 stores (8B) for the main C tile.
// MODE 1: GEMM2 split-K=4 — bf16 partials (4 x 4096x1024), Kp=K/4, grid 256.

template <int MODE>
__global__ __launch_bounds__(512, 2)
void gemm256_bt(const __hip_bfloat16* __restrict__ A,
                const __hip_bfloat16* __restrict__ Bt,
                __hip_bfloat16* __restrict__ Cout,
                float* __restrict__ dtraw, int K) {
  __shared__ __hip_bfloat16 smA[4][256 * 32];
  __shared__ __hip_bfloat16 smB[4][256 * 32];
  __shared__ __hip_bfloat16 smB2[4][48 * 32];   // MODE 0 remainder B tile (12 KB)

  int bm, bn, kbase, Kp;
  int q2 = 0;
  if constexpr (MODE == 0) {
    const int xcd = blockIdx.x & 7;
    const int i = blockIdx.x >> 3;            // 0..31
    bm = (xcd * 2 + (i & 1)) * 256;           // XCD owns 2 M-panels, m-fastest
    bn = (i >> 1) * 256;
    q2 = i >> 1;                              // 0..15
    kbase = 0; Kp = K;
  } else {
    const int s = blockIdx.x >> 6;            // 0..3 split
    const int bb = blockIdx.x & 63;
    const int xcd = bb & 7;
    const int i = bb >> 3;                    // 0..7
    bm = (xcd * 2 + (i & 1)) * 256;
    bn = (i >> 1) * 256;                      // 0..3 -> N=1024
    Kp = K >> 2; kbase = s * Kp;
  }
  const int tid = threadIdx.x;
  const int w = tid >> 6, lane = tid & 63;
  const int wm = w >> 2, wn = w & 3;
  const int fr = lane & 15, g = lane >> 4;
  const int srow = tid >> 2;                       // 0..127
  const int sc = (((tid & 3) ^ ((srow >> 1) & 3)) << 3);  // inverse-swizzled col
  const int rbase = (q2 & 1) * 128;                // remainder rows within block A tile

  f32x4 acc[8][4];
#pragma unroll
  for (int m = 0; m < 8; ++m)
#pragma unroll
    for (int n = 0; n < 4; ++n) acc[m][n] = (f32x4){0.f, 0.f, 0.f, 0.f};
  f32x4 acc2[3];
#pragma unroll
  for (int n = 0; n < 3; ++n) acc2[n] = (f32x4){0.f, 0.f, 0.f, 0.f};

  const __hip_bfloat16* aS = A + (size_t)(bm + srow) * K + kbase + sc;
  const __hip_bfloat16* bS = Bt + (size_t)(bn + srow) * K + kbase + sc;
  // remainder B rows (valid deref only for tid<192: srow<48)
  const __hip_bfloat16* bS2 = Bt + (size_t)(4096 + (q2 >> 1) * 48 + srow) * K + sc;
  const int dbase = w * 512;

  auto STAGE = [&](int buf, int kt) {
    const int k0 = kt << 5;
#pragma unroll
    for (int j = 0; j < 2; ++j) {
      __builtin_amdgcn_global_load_lds((const AS1 void*)(aS + (size_t)(j * 128) * K + k0),
                                       (AS3 void*)(&smA[buf][j * 4096 + dbase]), 16, 0, 0);
      __builtin_amdgcn_global_load_lds((const AS1 void*)(bS + (size_t)(j * 128) * K + k0),
                                       (AS3 void*)(&smB[buf][j * 4096 + dbase]), 16, 0, 0);
    }
    if constexpr (MODE == 0) {
      if (w < 3)
        __builtin_amdgcn_global_load_lds((const AS1 void*)(bS2 + k0),
                                         (AS3 void*)(&smB2[buf][dbase]), 16, 0, 0);
    }
  };

  const int nt = Kp >> 5;
  STAGE(0, 0);
  STAGE(1, 1);
  for (int kt = 0; kt < nt; ++kt) {
    const int cur = kt & 3;
    if (kt + 2 < nt) {
      STAGE((kt + 2) & 3, kt + 2);
      if constexpr (MODE == 0) {
        if (w < 3) { asm volatile("s_waitcnt vmcnt(10)" ::: "memory"); }
        else       { asm volatile("s_waitcnt vmcnt(8)" ::: "memory"); }
      } else {
        asm volatile("s_waitcnt vmcnt(8)" ::: "memory");
      }
    } else if (kt + 1 < nt) {
      if constexpr (MODE == 0) {
        if (w < 3) { asm volatile("s_waitcnt vmcnt(5)" ::: "memory"); }
        else       { asm volatile("s_waitcnt vmcnt(4)" ::: "memory"); }
      } else {
        asm volatile("s_waitcnt vmcnt(4)" ::: "memory");
      }
    } else {
      asm volatile("s_waitcnt vmcnt(0)" ::: "memory");
    }
    __builtin_amdgcn_s_barrier();
    __builtin_amdgcn_s_setprio(1);
    bf16x8 af[8], bfv[4];
#pragma unroll
    for (int m = 0; m < 8; ++m)
      af[m] = frag32(&smA[cur][0], wm * 128 + m * 16 + fr, g);
#pragma unroll
    for (int n = 0; n < 4; ++n)
      bfv[n] = frag32(&smB[cur][0], wn * 64 + n * 16 + fr, g);
#pragma unroll
    for (int m = 0; m < 8; ++m)
#pragma unroll
      for (int n = 0; n < 4; ++n)
        acc[m][n] = __builtin_amdgcn_mfma_f32_16x16x32_bf16(af[m], bfv[n], acc[m][n], 0, 0, 0);
    if constexpr (MODE == 0) {
      // fused remainder: wave w owns remainder rows rbase + w*16 .. +16
      bf16x8 a2 = frag32(&smA[cur][0], rbase + w * 16 + fr, g);
      bf16x8 b2[3];
#pragma unroll
      for (int n = 0; n < 3; ++n)
        b2[n] = frag32(&smB2[cur][0], n * 16 + fr, g);
#pragma unroll
      for (int n = 0; n < 3; ++n)
        acc2[n] = __builtin_amdgcn_mfma_f32_16x16x32_bf16(a2, b2[n], acc2[n], 0, 0, 0);
    }
    __builtin_amdgcn_s_setprio(0);
  }

  const int rb = g * 4;
  // ---- main epilogue: quadtr 4x4 transpose -> 8B stores ----
  // Lane holds col fr, rows g*4+0..3 of each 16x16 fragment. Quad = lanes sharing
  // (g, fr&~3): 4 rows x 4 cols block. After quadtr, lane ql=lane&3 holds row
  // g*4+ql, cols (fr&12)..+3 -> one ushort4 store.
  const int ql = lane & 3;
  const int cq = fr & 12;
#pragma unroll
  for (int m = 0; m < 8; ++m)
#pragma unroll
    for (int n = 0; n < 4; ++n) {
      ushort4 p = pack4(acc[m][n][0], acc[m][n][1], acc[m][n][2], acc[m][n][3]);
      unsigned a01 = (unsigned)p.x | ((unsigned)p.y << 16);
      unsigned a23 = (unsigned)p.z | ((unsigned)p.w << 16);
      unsigned w01, w23;
      quadtr(a01, a23, ql, w01, w23);
      uint2 v; v.x = w01; v.y = w23;
      int row = bm + wm * 128 + m * 16 + rb + ql;
      int col = bn + wn * 64 + n * 16 + cq;
      if constexpr (MODE == 0) {
        *reinterpret_cast<uint2*>(Cout + (size_t)row * NPAD + col) = v;
      } else {
        *reinterpret_cast<uint2*>(Cout + (size_t)(blockIdx.x >> 6) * 4194304 +
                                  (size_t)row * DMODEL + col) = v;
      }
    }

  if constexpr (MODE == 0) {
    // fused remainder epilogue (scalar: dt side-channel needs per-element f32)
    const int bn2 = 4096 + (q2 >> 1) * 48;
#pragma unroll
    for (int n = 0; n < 3; ++n) {
      int row = bm + rbase + w * 16 + rb;
      int col = bn2 + n * 16 + fr;
      __hip_bfloat16* cp = Cout + (size_t)row * NPAD + col;
#pragma unroll
      for (int j = 0; j < 4; ++j) {
        float v = acc2[n][j];
        cp[(size_t)j * NPAD] = __float2bfloat16(v);
        if (col >= DI + CONVD && col < DPROJ)
          dtraw[(size_t)(row + j) * NH + (col - (DI + CONVD))] = v;
      }
    }
  }
}

// ---------------- merged conv v4 (16 timesteps/thread) + chunk_stats ----------------
// blocks [0,576): conv 16 timesteps x 4 channels/thread; [576,832): chunk stats.

__global__ __launch_bounds__(256)
void conv_stats_kernel(const __hip_bfloat16* __restrict__ zxb,
                       const float* __restrict__ cw,
                       const float* __restrict__ cb,
                       __hip_bfloat16* __restrict__ xbc,
                       const float* __restrict__ dtraw, const float* __restrict__ dt_bias,
                       const float* __restrict__ A_log,
                       float* __restrict__ csb, float* __restrict__ dtc,
                       float* __restrict__ swb, float* __restrict__ cumdecb,
                       float* __restrict__ pbuf) {
  if (blockIdx.x >= 576) {
    // ---- chunk stats: one wave per (b,h,c) ----
    int w = threadIdx.x >> 6, lane = threadIdx.x & 63;
    int bid = (blockIdx.x - 576) * 4 + w;  // 0..1023
    int c = bid & (NCH - 1);
    int h = (bid >> 4) & 31;
    int b = bid >> 9;
    int t0 = c * QCH;
    float a = expf(A_log[h]);
    float bias = dt_bias[h];
    const float* dtp = dtraw + ((size_t)b * LSEQ + t0) * NH + h;
    float r0 = dtp[lane * NH] + bias;
    float r1 = dtp[(64 + lane) * NH] + bias;
    float v0 = (r0 > 20.f) ? r0 : log1pf(expf(r0));
    float v1 = (r1 > 20.f) ? r1 : log1pf(expf(r1));
    float s0 = v0;
#pragma unroll
    for (int off = 1; off < 64; off <<= 1) {
      float tv = __shfl_up(s0, off);
      if (lane >= off) s0 += tv;
    }
    float T0 = __shfl(s0, 63);
    float s1 = v1;
#pragma unroll
    for (int off = 1; off < 64; off <<= 1) {
      float tv = __shfl_up(s1, off);
      if (lane >= off) s1 += tv;
    }
    float cs1 = s1 + T0;
    float Tt = __shfl(s1, 63) + T0;
    size_t base = (size_t)bid * 128;
    csb[base + lane] = s0;        csb[base + 64 + lane] = cs1;
    dtc[base + lane] = v0;        dtc[base + 64 + lane] = v1;
    swb[base + lane] = v0 * expf(-a * (Tt - s0));
    swb[base + 64 + lane] = v1 * expf(-a * (Tt - cs1));
    cumdecb[base + lane] = expf(-a * s0);
    cumdecb[base + 64 + lane] = expf(-a * cs1);
    if (lane == 0) pbuf[bid] = expf(-a * Tt);
    return;
  }
  // ---- conv: 16 timesteps x 4 channels per thread ----
  int idx = blockIdx.x * 256 + threadIdx.x;    // 147456 = 2 b x 128 lchunk x 576 c4
  int c4 = idx % (CONVD / 4);
  int bl16 = idx / (CONVD / 4);
  int l0 = (bl16 & 127) * 16;
  int b = bl16 >> 7;
  int c0 = c4 * 4;
  const __hip_bfloat16* src = zxb + (size_t)b * LSEQ * NPAD + DI + c0;

  float wv[4][4];
#pragma unroll
  for (int j = 0; j < 4; ++j)
    *reinterpret_cast<float4*>(wv[j]) = *reinterpret_cast<const float4*>(cw + (c0 + j) * 4);
  float bias[4];
  *reinterpret_cast<float4*>(bias) = *reinterpret_cast<const float4*>(cb + c0);

  float hist[19][4];
#pragma unroll
  for (int r = 0; r < 19; ++r) {
    int row = l0 - 3 + r;
    if (row >= 0) {
      ushort4 v = *reinterpret_cast<const ushort4*>(src + (size_t)row * NPAD);
      hist[r][0] = bf2f(v.x); hist[r][1] = bf2f(v.y);
      hist[r][2] = bf2f(v.z); hist[r][3] = bf2f(v.w);
    } else {
#pragma unroll
      for (int j = 0; j < 4; ++j) hist[r][j] = 0.f;
    }
  }

#pragma unroll
  for (int t = 0; t < 16; ++t) {
    float acc[4];
#pragma unroll
    for (int j = 0; j < 4; ++j) {
      float a = bias[j];
      a = fmaf(wv[j][0], hist[t + 0][j], a);
      a = fmaf(wv[j][1], hist[t + 1][j], a);
      a = fmaf(wv[j][2], hist[t + 2][j], a);
      a = fmaf(wv[j][3], hist[t + 3][j], a);
      acc[j] = a / (1.f + expf(-a));
    }
    *reinterpret_cast<ushort4*>(xbc + ((size_t)b * LSEQ + l0 + t) * CONVD + c0) =
        pack4(acc[0], acc[1], acc[2], acc[3]);
  }
}

// ---------------- SSD pass 1: per-chunk MFMA ----------------
// Bw^T built from LDS (T_B) before P overwrites it; one extra barrier.

__global__ __launch_bounds__(256, 2)
void ssd_mfma_local(const __hip_bfloat16* __restrict__ bxc,
                    const float* __restrict__ csb, const float* __restrict__ dtc,
                    const float* __restrict__ swb,
                    const float* __restrict__ A_log, const float* __restrict__ Dparm,
                    __hip_bfloat16* __restrict__ y, __hip_bfloat16* __restrict__ sbuf) {
  __shared__ __hip_bfloat16 T_B[128 * 128];
  __shared__ __hip_bfloat16 T_C[128 * 128];
  __shared__ __hip_bfloat16 T_X[64 * 128];

  const int bid = blockIdx.x;
  const int c = bid & (NCH - 1);
  const int h = (bid >> 4) & 31;
  const int b = bid >> 9;
  const int tid = threadIdx.x;
  const int w = tid >> 6, lane = tid & 63;
  const int q = lane >> 2, ql = lane & 3;
  const int t0 = c * QCH;
  const __hip_bfloat16* xc = bxc + (size_t)b * LSEQ * CONVD;
  const float a = expf(A_log[h]);
  const float Dh = Dparm[h];

  {
    const int rsub = lane >> 4;
    const int ch = lane & 15;
#pragma unroll
    for (int j = 0; j < 8; ++j) {
      int row = w * 32 + j * 4 + rsub;
      int sc_ = ch ^ (row & 7);
      const __hip_bfloat16* pB = xc + (size_t)(t0 + row) * CONVD + DI + sc_ * 8;
      __builtin_amdgcn_global_load_lds((const AS1 void*)pB,
                                       (AS3 void*)(T_B + (w * 32 + j * 4) * 128), 16, 0, 0);
      __builtin_amdgcn_global_load_lds((const AS1 void*)(pB + DSTATE),
                                       (AS3 void*)(T_C + (w * 32 + j * 4) * 128), 16, 0, 0);
    }
  }
#pragma unroll
  for (int r = 0; r < 8; ++r) {
    int gidx = w * 128 + q * 8 + r;     // 0..511
    int tb = (gidx & 31) * 4;
    int pb = (gidx >> 5) * 4;
    int t = tb + ql;
    ushort4 xv = *reinterpret_cast<const ushort4*>(xc + (size_t)(t0 + t) * CONVD + h * HD + pb);
    unsigned a01 = (unsigned)xv.x | ((unsigned)xv.y << 16);
    unsigned a23 = (unsigned)xv.z | ((unsigned)xv.w << 16);
    unsigned w01, w23;
    quadtr(a01, a23, ql, w01, w23);
    ldswr8(T_X, pb + ql, tb, w01, w23);
  }
  __syncthreads();

  const int fr = lane & 15;
  const int fk = (lane >> 4) * 8;
  const int rb = (lane >> 4) * 4;

  // ---- phase 2: G^T[s][t] = sum_n B[s][n] C[t][n]; wave quadrant 64x64 ----
  const int sR0 = (w >> 1) * 64, tC0 = (w & 1) * 64;
  f32x4 g[4][4];
#pragma unroll
  for (int m = 0; m < 4; ++m)
#pragma unroll
    for (int n = 0; n < 4; ++n) g[m][n] = (f32x4){0.f, 0.f, 0.f, 0.f};
  for (int kk = 0; kk < 128; kk += 32) {
    bf16x8 af[4], bfv[4];
#pragma unroll
    for (int m = 0; m < 4; ++m) af[m] = ldsfrag(T_B, sR0 + m * 16 + fr, kk + fk);
#pragma unroll
    for (int n = 0; n < 4; ++n) bfv[n] = ldsfrag(T_C, tC0 + n * 16 + fr, kk + fk);
#pragma unroll
    for (int m = 0; m < 4; ++m)
#pragma unroll
      for (int n = 0; n < 4; ++n)
        g[m][n] = __builtin_amdgcn_mfma_f32_16x16x32_bf16(af[m], bfv[n], g[m][n], 0, 0, 0);
  }
  __syncthreads();  // all waves done reading T_B/T_C

  // ---- Bw^T build: read B from T_B (LDS), scale by w_t, quad-transpose -> T_C ----
  {
    const float* swp = swb + (size_t)bid * 128;
#pragma unroll
    for (int r = 0; r < 16; ++r) {
      int gidx = w * 256 + q * 16 + r;   // 0..1023
      int tb = (gidx & 31) * 4;
      int nb = (gidx >> 5) * 4;
      int t = tb + ql;
      ushort4 bv = ldsrd4(T_B, t, nb);
      float wt = swp[t];
      ushort4 sv = pack4(bf2f(bv.x) * wt, bf2f(bv.y) * wt, bf2f(bv.z) * wt, bf2f(bv.w) * wt);
      unsigned a01 = (unsigned)sv.x | ((unsigned)sv.y << 16);
      unsigned a23 = (unsigned)sv.z | ((unsigned)sv.w << 16);
      unsigned w01, w23;
      quadtr(a01, a23, ql, w01, w23);
      ldswr8(T_C, nb + ql, tb, w01, w23);
    }
  }
  __syncthreads();  // B reads of T_B done before P overwrites it

  // ---- mask L (+D diag) -> write P[t][s] into T_B ----
  {
    const float* csp = csb + (size_t)bid * 128;
    const float* dtp = dtc + (size_t)bid * 128;
#pragma unroll
    for (int m = 0; m < 4; ++m) {
      int sb0 = sR0 + m * 16 + rb;
      float cs_s[4], dt_s[4];
#pragma unroll
      for (int j = 0; j < 4; ++j) { cs_s[j] = csp[sb0 + j]; dt_s[j] = dtp[sb0 + j]; }
#pragma unroll
      for (int n = 0; n < 4; ++n) {
        int tt = tC0 + n * 16 + fr;
        float cst = csp[tt];
        float vv[4];
#pragma unroll
        for (int j = 0; j < 4; ++j) {
          int s = sb0 + j;
          float e = __expf(-a * (cst - cs_s[j])) * dt_s[j];
          float pv = (s <= tt) ? g[m][n][j] * e : 0.f;
          vv[j] = pv + ((s == tt) ? Dh : 0.f);
        }
        ldswr4(T_B, tt, sb0, pack4(vv[0], vv[1], vv[2], vv[3]));
      }
    }
  }
  __syncthreads();

  // ---- phase 3: Y[t][p] = sum_s P[t][s] X[s][p] -> bf16 ----
  {
    int tR0 = w * 32;
    f32x4 yac[2][4];
#pragma unroll
    for (int m = 0; m < 2; ++m)
#pragma unroll
      for (int n = 0; n < 4; ++n) yac[m][n] = (f32x4){0.f, 0.f, 0.f, 0.f};
    for (int kk = 0; kk < 128; kk += 32) {
      bf16x8 af[2], bfv[4];
#pragma unroll
      for (int m = 0; m < 2; ++m) af[m] = ldsfrag(T_B, tR0 + m * 16 + fr, kk + fk);
#pragma unroll
      for (int n = 0; n < 4; ++n) bfv[n] = ldsfrag(T_X, n * 16 + fr, kk + fk);
#pragma unroll
      for (int m = 0; m < 2; ++m)
#pragma unroll
        for (int n = 0; n < 4; ++n)
          yac[m][n] = __builtin_amdgcn_mfma_f32_16x16x32_bf16(af[m], bfv[n], yac[m][n], 0, 0, 0);
    }
#pragma unroll
    for (int m = 0; m < 2; ++m)
#pragma unroll
      for (int n = 0; n < 4; ++n) {
        int trow = tR0 + m * 16 + rb;
        int pc = n * 16 + fr;
        __hip_bfloat16* yp = y + ((size_t)b * LSEQ + t0 + trow) * DI + h * HD + pc;
#pragma unroll
        for (int j = 0; j < 4; ++j)
          yp[(size_t)j * DI] = __float2bfloat16(yac[m][n][j]);
      }
  }

  // ---- phase 4: S^T[p][n] = sum_t XT[p][t] BwT[n][t] -> sbuf[bid][p][n] ----
  {
    int pR0 = (w >> 1) * 32, nC0 = (w & 1) * 64;
    f32x4 sac[2][4];
#pragma unroll
    for (int m = 0; m < 2; ++m)
#pragma unroll
      for (int n = 0; n < 4; ++n) sac[m][n] = (f32x4){0.f, 0.f, 0.f, 0.f};
    for (int kk = 0; kk < 128; kk += 32) {
      bf16x8 af[2], bfv[4];
#pragma unroll
      for (int m = 0; m < 2; ++m) af[m] = ldsfrag(T_X, pR0 + m * 16 + fr, kk + fk);
#pragma unroll
      for (int n = 0; n < 4; ++n) bfv[n] = ldsfrag(T_C, nC0 + n * 16 + fr, kk + fk);
#pragma unroll
      for (int m = 0; m < 2; ++m)
#pragma unroll
        for (int n = 0; n < 4; ++n)
          sac[m][n] = __builtin_amdgcn_mfma_f32_16x16x32_bf16(af[m], bfv[n], sac[m][n], 0, 0, 0);
    }
    __hip_bfloat16* sg = sbuf + (size_t)bid * 8192;
#pragma unroll
    for (int m = 0; m < 2; ++m)
#pragma unroll
      for (int n = 0; n < 4; ++n) {
        int p = pR0 + m * 16 + rb;
        int nn = nC0 + n * 16 + fr;
#pragma unroll
        for (int j = 0; j < 4; ++j)
          sg[(size_t)(p + j) * 128 + nn] = __float2bfloat16(sac[m][n][j]);
      }
  }
}

// ---------------- SSD pass 2: propagate chunk states ----------------

__global__ void ssd_prop_kernel(__hip_bfloat16* __restrict__ sbuf,
                                const float* __restrict__ pbuf) {
  int idx = blockIdx.x * 256 + threadIdx.x;   // 64 * 8192
  int bh = idx >> 13;
  int e = idx & 8191;
  __hip_bfloat16* base = sbuf + (size_t)bh * NCH * 8192 + e;
  const float* pb = pbuf + bh * NCH;
  float hs = 0.f;
  for (int cc = 0; cc < NCH; ++cc) {
    float sc = __bfloat162float(base[(size_t)cc * 8192]);
    base[(size_t)cc * 8192] = __float2bfloat16(hs);
    hs = fmaf(hs, pb[cc], sc);
  }
}

// ---------------- SSD pass 3: Y += diag(cumdec) * C @ h_start (LDS-free) ----------------

__global__ __launch_bounds__(256, 4)
void ssd_mfma_corr(const __hip_bfloat16* __restrict__ bxc, const __hip_bfloat16* __restrict__ sbuf,
                   const float* __restrict__ cumdecb, __hip_bfloat16* __restrict__ y) {
  const int bid = (blockIdx.x / 15) * 16 + 1 + (blockIdx.x % 15);
  const int h = (bid >> 4) & 31;
  const int b = bid >> 9;
  const int tid = threadIdx.x;
  const int w = tid >> 6, lane = tid & 63;
  const int t0 = (bid & (NCH - 1)) * QCH;
  const __hip_bfloat16* xc = bxc + (size_t)b * LSEQ * CONVD;
  const __hip_bfloat16* hsb = sbuf + (size_t)bid * 8192;
  const int fr = lane & 15;
  const int fk = (lane >> 4) * 8;
  const int rb = (lane >> 4) * 4;
  const int tR0 = w * 32;

  f32x4 ac[2][4];
#pragma unroll
  for (int m = 0; m < 2; ++m)
#pragma unroll
    for (int n = 0; n < 4; ++n) ac[m][n] = (f32x4){0.f, 0.f, 0.f, 0.f};

#pragma unroll
  for (int kk = 0; kk < 128; kk += 32) {
    bf16x8 af[2], bfv[4];
#pragma unroll
    for (int m = 0; m < 2; ++m)
      af[m] = *reinterpret_cast<const bf16x8*>(
          xc + (size_t)(t0 + tR0 + m * 16 + fr) * CONVD + DI + DSTATE + kk + fk);
#pragma unroll
    for (int n = 0; n < 4; ++n)
      bfv[n] = *reinterpret_cast<const bf16x8*>(hsb + (size_t)(n * 16 + fr) * 128 + kk + fk);
#pragma unroll
    for (int m = 0; m < 2; ++m)
#pragma unroll
      for (int n = 0; n < 4; ++n)
        ac[m][n] = __builtin_amdgcn_mfma_f32_16x16x32_bf16(af[m], bfv[n], ac[m][n], 0, 0, 0);
  }

  const float* cdp = cumdecb + (size_t)bid * 128;
#pragma unroll
  for (int m = 0; m < 2; ++m) {
    int trow = tR0 + m * 16 + rb;
    float cd[4];
#pragma unroll
    for (int j = 0; j < 4; ++j) cd[j] = cdp[trow + j];
#pragma unroll
    for (int n = 0; n < 4; ++n) {
      int pc = n * 16 + fr;
      __hip_bfloat16* yp = y + ((size_t)b * LSEQ + t0 + trow) * DI + h * HD + pc;
#pragma unroll
      for (int j = 0; j < 4; ++j) {
        float old = __bfloat162float(yp[(size_t)j * DI]);
        yp[(size_t)j * DI] = __float2bfloat16(old + cd[j] * ac[m][n][j]);
      }
    }
  }
}

// ---------------- gating + RMS norm -> bf16 (8 cols/thread) ----------------

__global__ __launch_bounds__(256)
void gate_rms_kernel(const __hip_bfloat16* __restrict__ y, const __hip_bfloat16* __restrict__ zxb,
                     const float* __restrict__ nw, __hip_bfloat16* __restrict__ g) {
  int row = blockIdx.x;
  int t = threadIdx.x;
  int c0 = t * 8;
  const __hip_bfloat16* yr = y + (size_t)row * DI + c0;
  const __hip_bfloat16* zr = zxb + (size_t)row * NPAD + c0;
  ushort4 y0 = *reinterpret_cast<const ushort4*>(yr);
  ushort4 y1 = *reinterpret_cast<const ushort4*>(yr + 4);
  ushort4 z0 = *reinterpret_cast<const ushort4*>(zr);
  ushort4 z1 = *reinterpret_cast<const ushort4*>(zr + 4);
  float zf[8] = {bf2f(z0.x), bf2f(z0.y), bf2f(z0.z), bf2f(z0.w),
                 bf2f(z1.x), bf2f(z1.y), bf2f(z1.z), bf2f(z1.w)};
  float yf[8] = {bf2f(y0.x), bf2f(y0.y), bf2f(y0.z), bf2f(y0.w),
                 bf2f(y1.x), bf2f(y1.y), bf2f(y1.z), bf2f(y1.w)};
  float v[8];
  float ss = 0.f;
#pragma unroll
  for (int j = 0; j < 8; ++j) {
    float z = zf[j];
    float vv = yf[j] * (z / (1.f + expf(-z)));
    v[j] = vv;
    ss += vv * vv;
  }
#pragma unroll
  for (int off = 32; off; off >>= 1) ss += __shfl_down(ss, off);
  __shared__ float red[4];
  if ((t & 63) == 0) red[t >> 6] = ss;
  __syncthreads();
  float tot = red[0] + red[1] + red[2] + red[3];
  float rstd = rsqrtf(tot * (1.f / DI) + EPSV);
  float4 na = *reinterpret_cast<const float4*>(nw + c0);
  float4 nb = *reinterpret_cast<const float4*>(nw + c0 + 4);
  ushort4 o0 = pack4(v[0] * rstd * na.x, v[1] * rstd * na.y,
                     v[2] * rstd * na.z, v[3] * rstd * na.w);
  ushort4 o1v = pack4(v[4] * rstd * nb.x, v[5] * rstd * nb.y,
                      v[6] * rstd * nb.z, v[7] * rstd * nb.w);
  ushort4* gp = reinterpret_cast<ushort4*>(g + (size_t)row * DI + c0);
  gp[0] = o0;
  gp[1] = o1v;
}

// ---------------- final: sum 4 bf16 split-K partials, RMS, + residual ----------------

__global__ __launch_bounds__(256)
void final_rms_add(const __hip_bfloat16* __restrict__ o1p, const float* __restrict__ x,
                   float* __restrict__ out) {
  int row = blockIdx.x;
  int t = threadIdx.x;
  int c0 = t * 4;
  size_t off = (size_t)row * DMODEL + c0;
  float4 o = {0.f, 0.f, 0.f, 0.f};
#pragma unroll
  for (int s = 0; s < 4; ++s) {
    ushort4 p = *reinterpret_cast<const ushort4*>(o1p + (size_t)s * 4194304 + off);
    o.x += bf2f(p.x); o.y += bf2f(p.y); o.z += bf2f(p.z); o.w += bf2f(p.w);
  }
  float ss = o.x * o.x + o.y * o.y + o.z * o.z + o.w * o.w;
#pragma unroll
  for (int off2 = 32; off2; off2 >>= 1) ss += __shfl_down(ss, off2);
  __shared__ float red[4];
  if ((t & 63) == 0) red[t >> 6] = ss;
  __syncthreads();
  float tot = red[0] + red[1] + red[2] + red[3];
  float rstd = rsqrtf(tot * (1.f / DMODEL) + EPSV);
  float4 xv = *reinterpret_cast<const float4*>(x + off);
  float4 r;
  r.x = o.x * rstd + xv.x;
  r.y = o.y * rstd + xv.y;
  r.z = o.z * rstd + xv.z;
  r.w = o.w * rstd + xv.w;
  *reinterpret_cast<float4*>(out + off) = r;
}

// ---------------- launch ----------------

extern "C" void kernel_launch(void* const* d_in, const int* in_sizes, int n_in,
                              void* d_out, int out_size, void* d_ws, size_t ws_size,
                              hipStream_t stream) {
  const float* x       = (const float*)d_in[0];
  const float* W_in    = (const float*)d_in[1];
  const float* conv_w  = (const float*)d_in[2];
  const float* conv_b  = (const float*)d_in[3];
  const float* dt_bias = (const float*)d_in[4];
  const float* A_log   = (const float*)d_in[5];
  const float* Dp      = (const float*)d_in[6];
  const float* norm_w  = (const float*)d_in[7];
  const float* W_out   = (const float*)d_in[8];
  float* out = (float*)d_out;

  float* zxF  = (float*)d_ws;                               // slot holds zxb bf16 4096x4480
  __hip_bfloat16* zxb = (__hip_bfloat16*)zxF;
  __hip_bfloat16* o1p = zxb;   // overlay: zxb dead after gate_rms; 4 x 4096x1024 bf16
  float* xbcF = zxF + (size_t)18350080;                     // slot: 9437184 f32
  __hip_bfloat16* xbc = (__hip_bfloat16*)xbcF;              // 4096 x 2304 bf16
  float* ybufF = xbcF + (size_t)9437184;                    // slot: 8388608 f32
  __hip_bfloat16* ybuf = (__hip_bfloat16*)ybufF;            // 4096 x 2048 bf16
  float* dtraw = ybufF + (size_t)8388608;                   // 131072 (4096 x 32 f32)
  float* cumdecb = dtraw + (size_t)131072;                  // 131072 (1024 x 128)
  __hip_bfloat16* xbf   = (__hip_bfloat16*)(cumdecb + 131072); // 4096x1024
  __hip_bfloat16* wtin  = xbf + (size_t)4194304;               // 4480x1024
  __hip_bfloat16* wtout = wtin + (size_t)4587520;              // 1024x2048
  float* pbuf = (float*)(wtout + (size_t)2097152);             // 1024
  float* csb  = pbuf + 1024;                                   // 1024 x 128
  float* dtc  = csb + (size_t)131072;                          // 1024 x 128
  float* swb  = dtc + (size_t)131072;                          // 1024 x 128
  __hip_bfloat16* sbuf = xbf;  // overlay: xbf/wtin dead after GEMM1
  __hip_bfloat16* gbf = xbf;   // overlay: sbuf dead after ssd_mfma_corr

  prep_kernel<<<10624, 256, 0, stream>>>(x, xbf, W_in, wtin, W_out, wtout);

  // GEMM1: grid 256 — each block: 256^2 main tile with the 128x48 remainder tile
  // FUSED into the same K-pipeline (+dt side-channel). No tail phase.
  gemm256_bt<0><<<256, 512, 0, stream>>>(xbf, wtin, zxb, dtraw, 1024);

  conv_stats_kernel<<<832, 256, 0, stream>>>(zxb, conv_w, conv_b, xbc,
                                             dtraw, dt_bias, A_log,
                                             csb, dtc, swb, cumdecb, pbuf);

  ssd_mfma_local<<<1024, 256, 0, stream>>>(xbc, csb, dtc, swb, A_log, Dp, ybuf, sbuf);
  ssd_prop_kernel<<<2048, 256, 0, stream>>>(sbuf, pbuf);
  ssd_mfma_corr<<<960, 256, 0, stream>>>(xbc, sbuf, cumdecb, ybuf);

  gate_rms_kernel<<<4096, 256, 0, stream>>>(ybuf, zxb, norm_w, gbf);

  // GEMM2: 256^2 split-K=4 (grid 256 = 1/CU), bf16 partials into dead zxb slot.
  gemm256_bt<1><<<256, 512, 0, stream>>>(gbf, wtout, o1p, nullptr, 2048);

  final_rms_add<<<4096, 256, 0, stream>>>(o1p, x, out);
}

// Round 28
// 172.995 us; speedup vs baseline: 1.0314x; 1.0314x over previous
//
#include <hip/hip_runtime.h>
#include <hip/hip_bf16.h>

#define DMODEL 1024
#define DI     2048
#define DSTATE 128
#define NH     32
#define HD     64
#define CONVD  2304
#define LSEQ   2048
#define BATCH  2
#define DPROJ  4384
#define NPAD   4480      // zxb column stride
#define EPSV   1e-5f
#define QCH    128
#define NCH    16

#define AS1 __attribute__((address_space(1)))
#define AS3 __attribute__((address_space(3)))

typedef __attribute__((ext_vector_type(8))) short bf16x8;
typedef __attribute__((ext_vector_type(4))) float f32x4;

union U4 { ushort4 u; __hip_bfloat16 h[4]; };

__device__ __forceinline__ float bf2f(unsigned short u) {
  union { unsigned int i; float f; } c; c.i = ((unsigned)u) << 16; return c.f;
}
__device__ __forceinline__ ushort4 pack4(float x0, float x1, float x2, float x3) {
  U4 p;
  p.h[0] = __float2bfloat16(x0); p.h[1] = __float2bfloat16(x1);
  p.h[2] = __float2bfloat16(x2); p.h[3] = __float2bfloat16(x3);
  return p.u;
}

// ---- swizzled LDS helpers: [rows][128] bf16 tiles (256B rows), byte ^= (row&7)<<4 ----
__device__ __forceinline__ bf16x8 ldsfrag(const __hip_bfloat16* base, int row, int ke) {
  int byte = row * 256 + ke * 2;
  byte ^= (row & 7) << 4;
  return *reinterpret_cast<const bf16x8*>(reinterpret_cast<const char*>(base) + byte);
}
__device__ __forceinline__ void ldswr4(__hip_bfloat16* base, int row, int col, ushort4 v) {
  int byte = row * 256 + col * 2;
  byte ^= (row & 7) << 4;
  *reinterpret_cast<ushort4*>(reinterpret_cast<char*>(base) + byte) = v;
}
__device__ __forceinline__ ushort4 ldsrd4(const __hip_bfloat16* base, int row, int col) {
  int byte = row * 256 + col * 2;
  byte ^= (row & 7) << 4;
  return *reinterpret_cast<const ushort4*>(reinterpret_cast<const char*>(base) + byte);
}
__device__ __forceinline__ void ldswr8(__hip_bfloat16* base, int row, int colElem,
                                       unsigned lo, unsigned hi) {
  int byte = row * 256 + colElem * 2;
  byte ^= (row & 7) << 4;
  uint2 v; v.x = lo; v.y = hi;
  *reinterpret_cast<uint2*>(reinterpret_cast<char*>(base) + byte) = v;
}
// ---- swizzled helper for [rows][32] bf16 tiles (64B rows): chunk g ^= (row>>1)&3 ----
__device__ __forceinline__ bf16x8 frag32(const __hip_bfloat16* base, int row, int g) {
  int byte = row * 64 + (((g ^ (row >> 1)) & 3) << 4);
  return *reinterpret_cast<const bf16x8*>(reinterpret_cast<const char*>(base) + byte);
}

// ---- in-register 4x4 u16 transpose across a quad (lanes ql=0..3) ----
__device__ __forceinline__ void quadtr(unsigned a01, unsigned a23, int ql,
                                       unsigned& w01, unsigned& w23) {
  unsigned y01 = __shfl_xor((int)a01, 1), y23 = __shfl_xor((int)a23, 1);
  unsigned c01 = (ql & 1) ? ((y01 >> 16) | (a01 & 0xFFFF0000u))
                          : ((a01 & 0xFFFFu) | (y01 << 16));
  unsigned c23 = (ql & 1) ? ((y23 >> 16) | (a23 & 0xFFFF0000u))
                          : ((a23 & 0xFFFFu) | (y23 << 16));
  unsigned d01 = __shfl_xor((int)c01, 2), d23 = __shfl_xor((int)c23, 2);
  w01 = (ql & 2) ? d23 : c01;
  w23 = (ql & 2) ? c23 : d01;
}

// ---------------- merged prep: x->bf16 + W_in^T + W_out^T in one launch ----------------

__global__ __launch_bounds__(256)
void prep_kernel(const float* __restrict__ x, __hip_bfloat16* __restrict__ xbf,
                 const float* __restrict__ W_in, __hip_bfloat16* __restrict__ wtin,
                 const float* __restrict__ W_out, __hip_bfloat16* __restrict__ wtout) {
  __shared__ float tile[32][33];
  const int b = blockIdx.x, tid = threadIdx.x;
  if (b < 4096) {
    int i = b * 256 + tid;
    float4 v = reinterpret_cast<const float4*>(x)[i];
    reinterpret_cast<ushort4*>(xbf)[i] = pack4(v.x, v.y, v.z, v.w);
    return;
  }
  const float* in;
  __hip_bfloat16* outp;
  int R, C, Cpad, n0, k0;
  if (b < 4096 + 4480) {
    int t = b - 4096;
    in = W_in; outp = wtin; R = 1024; C = 4384; Cpad = 4480;
    n0 = (t % 140) * 32; k0 = (t / 140) * 32;
  } else {
    int t = b - 8576;
    in = W_out; outp = wtout; R = 2048; C = 1024; Cpad = 1024;
    n0 = (t % 32) * 32; k0 = (t / 32) * 32;
  }
  int tx = tid & 31, ty = tid >> 5;
#pragma unroll
  for (int j = 0; j < 32; j += 8) {
    int k = k0 + ty + j, n = n0 + tx;
    tile[ty + j][tx] = (n < C) ? in[(size_t)k * C + n] : 0.f;
  }
  __syncthreads();
#pragma unroll
  for (int j = 0; j < 32; j += 8) {
    int n = n0 + ty + j, k = k0 + tx;
    if (n < Cpad) outp[(size_t)n * R + k] = __float2bfloat16(tile[tx][ty + j]);
  }
}

// ---------------- GEMM 256x256: BK=32, 4-buffer depth-2 counted-vmcnt ----------------
// MODE 0: GEMM1 — grid 256; block (p=bm/256, q=bn/256) computes its 256^2 main tile
//         AND the remainder tile {rows p*256+(q&1)*128..+128, cols 4096+(q>>1)*48..+48}
//         FUSED into the same K-pipeline (B2 staged by waves 0-2). +dt side-channel.
// MODE 1: GEMM2 split-K=4 — bf16 partials (4 x 4096x1024), Kp=K/4, grid 256.

template <int MODE>
__global__ __launch_bounds__(512, 2)
void gemm256_bt(const __hip_bfloat16* __restrict__ A,
                const __hip_bfloat16* __restrict__ Bt,
                __hip_bfloat16* __restrict__ Cout,
                float* __restrict__ dtraw, int K) {
  __shared__ __hip_bfloat16 smA[4][256 * 32];
  __shared__ __hip_bfloat16 smB[4][256 * 32];
  __shared__ __hip_bfloat16 smB2[4][48 * 32];   // MODE 0 remainder B tile (12 KB)

  int bm, bn, kbase, Kp;
  int q2 = 0;
  if constexpr (MODE == 0) {
    const int xcd = blockIdx.x & 7;
    const int i = blockIdx.x >> 3;            // 0..31
    bm = (xcd * 2 + (i & 1)) * 256;           // XCD owns 2 M-panels, m-fastest
    bn = (i >> 1) * 256;
    q2 = i >> 1;                              // 0..15
    kbase = 0; Kp = K;
  } else {
    const int s = blockIdx.x >> 6;            // 0..3 split
    const int bb = blockIdx.x & 63;
    const int xcd = bb & 7;
    const int i = bb >> 3;                    // 0..7
    bm = (xcd * 2 + (i & 1)) * 256;
    bn = (i >> 1) * 256;                      // 0..3 -> N=1024
    Kp = K >> 2; kbase = s * Kp;
  }
  const int tid = threadIdx.x;
  const int w = tid >> 6, lane = tid & 63;
  const int wm = w >> 2, wn = w & 3;
  const int fr = lane & 15, g = lane >> 4;
  const int srow = tid >> 2;                       // 0..127
  const int sc = (((tid & 3) ^ ((srow >> 1) & 3)) << 3);  // inverse-swizzled col
  const int rbase = (q2 & 1) * 128;                // remainder rows within block A tile

  f32x4 acc[8][4];
#pragma unroll
  for (int m = 0; m < 8; ++m)
#pragma unroll
    for (int n = 0; n < 4; ++n) acc[m][n] = (f32x4){0.f, 0.f, 0.f, 0.f};
  f32x4 acc2[3];
#pragma unroll
  for (int n = 0; n < 3; ++n) acc2[n] = (f32x4){0.f, 0.f, 0.f, 0.f};

  const __hip_bfloat16* aS = A + (size_t)(bm + srow) * K + kbase + sc;
  const __hip_bfloat16* bS = Bt + (size_t)(bn + srow) * K + kbase + sc;
  // remainder B rows (valid deref only for tid<192: srow<48)
  const __hip_bfloat16* bS2 = Bt + (size_t)(4096 + (q2 >> 1) * 48 + srow) * K + sc;
  const int dbase = w * 512;

  auto STAGE = [&](int buf, int kt) {
    const int k0 = kt << 5;
#pragma unroll
    for (int j = 0; j < 2; ++j) {
      __builtin_amdgcn_global_load_lds((const AS1 void*)(aS + (size_t)(j * 128) * K + k0),
                                       (AS3 void*)(&smA[buf][j * 4096 + dbase]), 16, 0, 0);
      __builtin_amdgcn_global_load_lds((const AS1 void*)(bS + (size_t)(j * 128) * K + k0),
                                       (AS3 void*)(&smB[buf][j * 4096 + dbase]), 16, 0, 0);
    }
    if constexpr (MODE == 0) {
      if (w < 3)
        __builtin_amdgcn_global_load_lds((const AS1 void*)(bS2 + k0),
                                         (AS3 void*)(&smB2[buf][dbase]), 16, 0, 0);
    }
  };

  const int nt = Kp >> 5;
  STAGE(0, 0);
  STAGE(1, 1);
  for (int kt = 0; kt < nt; ++kt) {
    const int cur = kt & 3;
    if (kt + 2 < nt) {
      STAGE((kt + 2) & 3, kt + 2);
      if constexpr (MODE == 0) {
        if (w < 3) { asm volatile("s_waitcnt vmcnt(10)" ::: "memory"); }
        else       { asm volatile("s_waitcnt vmcnt(8)" ::: "memory"); }
      } else {
        asm volatile("s_waitcnt vmcnt(8)" ::: "memory");
      }
    } else if (kt + 1 < nt) {
      if constexpr (MODE == 0) {
        if (w < 3) { asm volatile("s_waitcnt vmcnt(5)" ::: "memory"); }
        else       { asm volatile("s_waitcnt vmcnt(4)" ::: "memory"); }
      } else {
        asm volatile("s_waitcnt vmcnt(4)" ::: "memory");
      }
    } else {
      asm volatile("s_waitcnt vmcnt(0)" ::: "memory");
    }
    __builtin_amdgcn_s_barrier();
    __builtin_amdgcn_s_setprio(1);
    bf16x8 af[8], bfv[4];
#pragma unroll
    for (int m = 0; m < 8; ++m)
      af[m] = frag32(&smA[cur][0], wm * 128 + m * 16 + fr, g);
#pragma unroll
    for (int n = 0; n < 4; ++n)
      bfv[n] = frag32(&smB[cur][0], wn * 64 + n * 16 + fr, g);
#pragma unroll
    for (int m = 0; m < 8; ++m)
#pragma unroll
      for (int n = 0; n < 4; ++n)
        acc[m][n] = __builtin_amdgcn_mfma_f32_16x16x32_bf16(af[m], bfv[n], acc[m][n], 0, 0, 0);
    if constexpr (MODE == 0) {
      // fused remainder: wave w owns remainder rows rbase + w*16 .. +16
      bf16x8 a2 = frag32(&smA[cur][0], rbase + w * 16 + fr, g);
      bf16x8 b2[3];
#pragma unroll
      for (int n = 0; n < 3; ++n)
        b2[n] = frag32(&smB2[cur][0], n * 16 + fr, g);
#pragma unroll
      for (int n = 0; n < 3; ++n)
        acc2[n] = __builtin_amdgcn_mfma_f32_16x16x32_bf16(a2, b2[n], acc2[n], 0, 0, 0);
    }
    __builtin_amdgcn_s_setprio(0);
  }

  const int rb = g * 4;
#pragma unroll
  for (int m = 0; m < 8; ++m)
#pragma unroll
    for (int n = 0; n < 4; ++n) {
      int row = bm + wm * 128 + m * 16 + rb;
      int col = bn + wn * 64 + n * 16 + fr;
      if constexpr (MODE == 0) {
        __hip_bfloat16* cp = Cout + (size_t)row * NPAD + col;
#pragma unroll
        for (int j = 0; j < 4; ++j)
          cp[(size_t)j * NPAD] = __float2bfloat16(acc[m][n][j]);
      } else {
        __hip_bfloat16* cp = Cout + (size_t)(blockIdx.x >> 6) * 4194304 +
                             (size_t)row * DMODEL + col;
#pragma unroll
        for (int j = 0; j < 4; ++j)
          cp[(size_t)j * DMODEL] = __float2bfloat16(acc[m][n][j]);
      }
    }

  if constexpr (MODE == 0) {
    // fused remainder epilogue: rows bm+rbase+w*16.., cols 4096+(q2>>1)*48..
    const int bn2 = 4096 + (q2 >> 1) * 48;
#pragma unroll
    for (int n = 0; n < 3; ++n) {
      int row = bm + rbase + w * 16 + rb;
      int col = bn2 + n * 16 + fr;
      __hip_bfloat16* cp = Cout + (size_t)row * NPAD + col;
#pragma unroll
      for (int j = 0; j < 4; ++j) {
        float v = acc2[n][j];
        cp[(size_t)j * NPAD] = __float2bfloat16(v);
        if (col >= DI + CONVD && col < DPROJ)
          dtraw[(size_t)(row + j) * NH + (col - (DI + CONVD))] = v;
      }
    }
  }
}

// ---------------- merged conv v4 (16 timesteps/thread) + chunk_stats ----------------
// blocks [0,576): conv 16 timesteps x 4 channels/thread; [576,832): chunk stats.

__global__ __launch_bounds__(256)
void conv_stats_kernel(const __hip_bfloat16* __restrict__ zxb,
                       const float* __restrict__ cw,
                       const float* __restrict__ cb,
                       __hip_bfloat16* __restrict__ xbc,
                       const float* __restrict__ dtraw, const float* __restrict__ dt_bias,
                       const float* __restrict__ A_log,
                       float* __restrict__ csb, float* __restrict__ dtc,
                       float* __restrict__ swb, float* __restrict__ cumdecb,
                       float* __restrict__ pbuf) {
  if (blockIdx.x >= 576) {
    // ---- chunk stats: one wave per (b,h,c) ----
    int w = threadIdx.x >> 6, lane = threadIdx.x & 63;
    int bid = (blockIdx.x - 576) * 4 + w;  // 0..1023
    int c = bid & (NCH - 1);
    int h = (bid >> 4) & 31;
    int b = bid >> 9;
    int t0 = c * QCH;
    float a = expf(A_log[h]);
    float bias = dt_bias[h];
    const float* dtp = dtraw + ((size_t)b * LSEQ + t0) * NH + h;
    float r0 = dtp[lane * NH] + bias;
    float r1 = dtp[(64 + lane) * NH] + bias;
    float v0 = (r0 > 20.f) ? r0 : log1pf(expf(r0));
    float v1 = (r1 > 20.f) ? r1 : log1pf(expf(r1));
    float s0 = v0;
#pragma unroll
    for (int off = 1; off < 64; off <<= 1) {
      float tv = __shfl_up(s0, off);
      if (lane >= off) s0 += tv;
    }
    float T0 = __shfl(s0, 63);
    float s1 = v1;
#pragma unroll
    for (int off = 1; off < 64; off <<= 1) {
      float tv = __shfl_up(s1, off);
      if (lane >= off) s1 += tv;
    }
    float cs1 = s1 + T0;
    float Tt = __shfl(s1, 63) + T0;
    size_t base = (size_t)bid * 128;
    csb[base + lane] = s0;        csb[base + 64 + lane] = cs1;
    dtc[base + lane] = v0;        dtc[base + 64 + lane] = v1;
    swb[base + lane] = v0 * expf(-a * (Tt - s0));
    swb[base + 64 + lane] = v1 * expf(-a * (Tt - cs1));
    cumdecb[base + lane] = expf(-a * s0);
    cumdecb[base + 64 + lane] = expf(-a * cs1);
    if (lane == 0) pbuf[bid] = expf(-a * Tt);
    return;
  }
  // ---- conv: 16 timesteps x 4 channels per thread ----
  int idx = blockIdx.x * 256 + threadIdx.x;    // 147456 = 2 b x 128 lchunk x 576 c4
  int c4 = idx % (CONVD / 4);
  int bl16 = idx / (CONVD / 4);
  int l0 = (bl16 & 127) * 16;
  int b = bl16 >> 7;
  int c0 = c4 * 4;
  const __hip_bfloat16* src = zxb + (size_t)b * LSEQ * NPAD + DI + c0;

  float wv[4][4];
#pragma unroll
  for (int j = 0; j < 4; ++j)
    *reinterpret_cast<float4*>(wv[j]) = *reinterpret_cast<const float4*>(cw + (c0 + j) * 4);
  float bias[4];
  *reinterpret_cast<float4*>(bias) = *reinterpret_cast<const float4*>(cb + c0);

  float hist[19][4];
#pragma unroll
  for (int r = 0; r < 19; ++r) {
    int row = l0 - 3 + r;
    if (row >= 0) {
      ushort4 v = *reinterpret_cast<const ushort4*>(src + (size_t)row * NPAD);
      hist[r][0] = bf2f(v.x); hist[r][1] = bf2f(v.y);
      hist[r][2] = bf2f(v.z); hist[r][3] = bf2f(v.w);
    } else {
#pragma unroll
      for (int j = 0; j < 4; ++j) hist[r][j] = 0.f;
    }
  }

#pragma unroll
  for (int t = 0; t < 16; ++t) {
    float acc[4];
#pragma unroll
    for (int j = 0; j < 4; ++j) {
      float a = bias[j];
      a = fmaf(wv[j][0], hist[t + 0][j], a);
      a = fmaf(wv[j][1], hist[t + 1][j], a);
      a = fmaf(wv[j][2], hist[t + 2][j], a);
      a = fmaf(wv[j][3], hist[t + 3][j], a);
      acc[j] = a / (1.f + expf(-a));
    }
    *reinterpret_cast<ushort4*>(xbc + ((size_t)b * LSEQ + l0 + t) * CONVD + c0) =
        pack4(acc[0], acc[1], acc[2], acc[3]);
  }
}

// ---------------- SSD pass 1: per-chunk MFMA ----------------
// Bw^T built from LDS (T_B) before P overwrites it; one extra barrier.

__global__ __launch_bounds__(256, 2)
void ssd_mfma_local(const __hip_bfloat16* __restrict__ bxc,
                    const float* __restrict__ csb, const float* __restrict__ dtc,
                    const float* __restrict__ swb,
                    const float* __restrict__ A_log, const float* __restrict__ Dparm,
                    __hip_bfloat16* __restrict__ y, __hip_bfloat16* __restrict__ sbuf) {
  __shared__ __hip_bfloat16 T_B[128 * 128];
  __shared__ __hip_bfloat16 T_C[128 * 128];
  __shared__ __hip_bfloat16 T_X[64 * 128];

  const int bid = blockIdx.x;
  const int c = bid & (NCH - 1);
  const int h = (bid >> 4) & 31;
  const int b = bid >> 9;
  const int tid = threadIdx.x;
  const int w = tid >> 6, lane = tid & 63;
  const int q = lane >> 2, ql = lane & 3;
  const int t0 = c * QCH;
  const __hip_bfloat16* xc = bxc + (size_t)b * LSEQ * CONVD;
  const float a = expf(A_log[h]);
  const float Dh = Dparm[h];

  {
    const int rsub = lane >> 4;
    const int ch = lane & 15;
#pragma unroll
    for (int j = 0; j < 8; ++j) {
      int row = w * 32 + j * 4 + rsub;
      int sc_ = ch ^ (row & 7);
      const __hip_bfloat16* pB = xc + (size_t)(t0 + row) * CONVD + DI + sc_ * 8;
      __builtin_amdgcn_global_load_lds((const AS1 void*)pB,
                                       (AS3 void*)(T_B + (w * 32 + j * 4) * 128), 16, 0, 0);
      __builtin_amdgcn_global_load_lds((const AS1 void*)(pB + DSTATE),
                                       (AS3 void*)(T_C + (w * 32 + j * 4) * 128), 16, 0, 0);
    }
  }
#pragma unroll
  for (int r = 0; r < 8; ++r) {
    int gidx = w * 128 + q * 8 + r;     // 0..511
    int tb = (gidx & 31) * 4;
    int pb = (gidx >> 5) * 4;
    int t = tb + ql;
    ushort4 xv = *reinterpret_cast<const ushort4*>(xc + (size_t)(t0 + t) * CONVD + h * HD + pb);
    unsigned a01 = (unsigned)xv.x | ((unsigned)xv.y << 16);
    unsigned a23 = (unsigned)xv.z | ((unsigned)xv.w << 16);
    unsigned w01, w23;
    quadtr(a01, a23, ql, w01, w23);
    ldswr8(T_X, pb + ql, tb, w01, w23);
  }
  __syncthreads();

  const int fr = lane & 15;
  const int fk = (lane >> 4) * 8;
  const int rb = (lane >> 4) * 4;

  // ---- phase 2: G^T[s][t] = sum_n B[s][n] C[t][n]; wave quadrant 64x64 ----
  const int sR0 = (w >> 1) * 64, tC0 = (w & 1) * 64;
  f32x4 g[4][4];
#pragma unroll
  for (int m = 0; m < 4; ++m)
#pragma unroll
    for (int n = 0; n < 4; ++n) g[m][n] = (f32x4){0.f, 0.f, 0.f, 0.f};
  for (int kk = 0; kk < 128; kk += 32) {
    bf16x8 af[4], bfv[4];
#pragma unroll
    for (int m = 0; m < 4; ++m) af[m] = ldsfrag(T_B, sR0 + m * 16 + fr, kk + fk);
#pragma unroll
    for (int n = 0; n < 4; ++n) bfv[n] = ldsfrag(T_C, tC0 + n * 16 + fr, kk + fk);
#pragma unroll
    for (int m = 0; m < 4; ++m)
#pragma unroll
      for (int n = 0; n < 4; ++n)
        g[m][n] = __builtin_amdgcn_mfma_f32_16x16x32_bf16(af[m], bfv[n], g[m][n], 0, 0, 0);
  }
  __syncthreads();  // all waves done reading T_B/T_C

  // ---- Bw^T build: read B from T_B (LDS), scale by w_t, quad-transpose -> T_C ----
  {
    const float* swp = swb + (size_t)bid * 128;
#pragma unroll
    for (int r = 0; r < 16; ++r) {
      int gidx = w * 256 + q * 16 + r;   // 0..1023
      int tb = (gidx & 31) * 4;
      int nb = (gidx >> 5) * 4;
      int t = tb + ql;
      ushort4 bv = ldsrd4(T_B, t, nb);
      float wt = swp[t];
      ushort4 sv = pack4(bf2f(bv.x) * wt, bf2f(bv.y) * wt, bf2f(bv.z) * wt, bf2f(bv.w) * wt);
      unsigned a01 = (unsigned)sv.x | ((unsigned)sv.y << 16);
      unsigned a23 = (unsigned)sv.z | ((unsigned)sv.w << 16);
      unsigned w01, w23;
      quadtr(a01, a23, ql, w01, w23);
      ldswr8(T_C, nb + ql, tb, w01, w23);
    }
  }
  __syncthreads();  // B reads of T_B done before P overwrites it

  // ---- mask L (+D diag) -> write P[t][s] into T_B ----
  {
    const float* csp = csb + (size_t)bid * 128;
    const float* dtp = dtc + (size_t)bid * 128;
#pragma unroll
    for (int m = 0; m < 4; ++m) {
      int sb0 = sR0 + m * 16 + rb;
      float cs_s[4], dt_s[4];
#pragma unroll
      for (int j = 0; j < 4; ++j) { cs_s[j] = csp[sb0 + j]; dt_s[j] = dtp[sb0 + j]; }
#pragma unroll
      for (int n = 0; n < 4; ++n) {
        int tt = tC0 + n * 16 + fr;
        float cst = csp[tt];
        float vv[4];
#pragma unroll
        for (int j = 0; j < 4; ++j) {
          int s = sb0 + j;
          float e = __expf(-a * (cst - cs_s[j])) * dt_s[j];
          float pv = (s <= tt) ? g[m][n][j] * e : 0.f;
          vv[j] = pv + ((s == tt) ? Dh : 0.f);
        }
        ldswr4(T_B, tt, sb0, pack4(vv[0], vv[1], vv[2], vv[3]));
      }
    }
  }
  __syncthreads();

  // ---- phase 3: Y[t][p] = sum_s P[t][s] X[s][p] -> bf16 ----
  {
    int tR0 = w * 32;
    f32x4 yac[2][4];
#pragma unroll
    for (int m = 0; m < 2; ++m)
#pragma unroll
      for (int n = 0; n < 4; ++n) yac[m][n] = (f32x4){0.f, 0.f, 0.f, 0.f};
    for (int kk = 0; kk < 128; kk += 32) {
      bf16x8 af[2], bfv[4];
#pragma unroll
      for (int m = 0; m < 2; ++m) af[m] = ldsfrag(T_B, tR0 + m * 16 + fr, kk + fk);
#pragma unroll
      for (int n = 0; n < 4; ++n) bfv[n] = ldsfrag(T_X, n * 16 + fr, kk + fk);
#pragma unroll
      for (int m = 0; m < 2; ++m)
#pragma unroll
        for (int n = 0; n < 4; ++n)
          yac[m][n] = __builtin_amdgcn_mfma_f32_16x16x32_bf16(af[m], bfv[n], yac[m][n], 0, 0, 0);
    }
#pragma unroll
    for (int m = 0; m < 2; ++m)
#pragma unroll
      for (int n = 0; n < 4; ++n) {
        int trow = tR0 + m * 16 + rb;
        int pc = n * 16 + fr;
        __hip_bfloat16* yp = y + ((size_t)b * LSEQ + t0 + trow) * DI + h * HD + pc;
#pragma unroll
        for (int j = 0; j < 4; ++j)
          yp[(size_t)j * DI] = __float2bfloat16(yac[m][n][j]);
      }
  }

  // ---- phase 4: S^T[p][n] = sum_t XT[p][t] BwT[n][t] -> sbuf[bid][p][n] ----
  {
    int pR0 = (w >> 1) * 32, nC0 = (w & 1) * 64;
    f32x4 sac[2][4];
#pragma unroll
    for (int m = 0; m < 2; ++m)
#pragma unroll
      for (int n = 0; n < 4; ++n) sac[m][n] = (f32x4){0.f, 0.f, 0.f, 0.f};
    for (int kk = 0; kk < 128; kk += 32) {
      bf16x8 af[2], bfv[4];
#pragma unroll
      for (int m = 0; m < 2; ++m) af[m] = ldsfrag(T_X, pR0 + m * 16 + fr, kk + fk);
#pragma unroll
      for (int n = 0; n < 4; ++n) bfv[n] = ldsfrag(T_C, nC0 + n * 16 + fr, kk + fk);
#pragma unroll
      for (int m = 0; m < 2; ++m)
#pragma unroll
        for (int n = 0; n < 4; ++n)
          sac[m][n] = __builtin_amdgcn_mfma_f32_16x16x32_bf16(af[m], bfv[n], sac[m][n], 0, 0, 0);
    }
    __hip_bfloat16* sg = sbuf + (size_t)bid * 8192;
#pragma unroll
    for (int m = 0; m < 2; ++m)
#pragma unroll
      for (int n = 0; n < 4; ++n) {
        int p = pR0 + m * 16 + rb;
        int nn = nC0 + n * 16 + fr;
#pragma unroll
        for (int j = 0; j < 4; ++j)
          sg[(size_t)(p + j) * 128 + nn] = __float2bfloat16(sac[m][n][j]);
      }
  }
}

// ---------------- SSD pass 2: propagate chunk states ----------------

__global__ void ssd_prop_kernel(__hip_bfloat16* __restrict__ sbuf,
                                const float* __restrict__ pbuf) {
  int idx = blockIdx.x * 256 + threadIdx.x;   // 64 * 8192
  int bh = idx >> 13;
  int e = idx & 8191;
  __hip_bfloat16* base = sbuf + (size_t)bh * NCH * 8192 + e;
  const float* pb = pbuf + bh * NCH;
  float hs = 0.f;
  for (int cc = 0; cc < NCH; ++cc) {
    float sc = __bfloat162float(base[(size_t)cc * 8192]);
    base[(size_t)cc * 8192] = __float2bfloat16(hs);
    hs = fmaf(hs, pb[cc], sc);
  }
}

// ---------------- SSD pass 3: Y += diag(cumdec) * C @ h_start (LDS-free) ----------------

__global__ __launch_bounds__(256, 4)
void ssd_mfma_corr(const __hip_bfloat16* __restrict__ bxc, const __hip_bfloat16* __restrict__ sbuf,
                   const float* __restrict__ cumdecb, __hip_bfloat16* __restrict__ y) {
  const int bid = (blockIdx.x / 15) * 16 + 1 + (blockIdx.x % 15);
  const int h = (bid >> 4) & 31;
  const int b = bid >> 9;
  const int tid = threadIdx.x;
  const int w = tid >> 6, lane = tid & 63;
  const int t0 = (bid & (NCH - 1)) * QCH;
  const __hip_bfloat16* xc = bxc + (size_t)b * LSEQ * CONVD;
  const __hip_bfloat16* hsb = sbuf + (size_t)bid * 8192;
  const int fr = lane & 15;
  const int fk = (lane >> 4) * 8;
  const int rb = (lane >> 4) * 4;
  const int tR0 = w * 32;

  f32x4 ac[2][4];
#pragma unroll
  for (int m = 0; m < 2; ++m)
#pragma unroll
    for (int n = 0; n < 4; ++n) ac[m][n] = (f32x4){0.f, 0.f, 0.f, 0.f};

#pragma unroll
  for (int kk = 0; kk < 128; kk += 32) {
    bf16x8 af[2], bfv[4];
#pragma unroll
    for (int m = 0; m < 2; ++m)
      af[m] = *reinterpret_cast<const bf16x8*>(
          xc + (size_t)(t0 + tR0 + m * 16 + fr) * CONVD + DI + DSTATE + kk + fk);
#pragma unroll
    for (int n = 0; n < 4; ++n)
      bfv[n] = *reinterpret_cast<const bf16x8*>(hsb + (size_t)(n * 16 + fr) * 128 + kk + fk);
#pragma unroll
    for (int m = 0; m < 2; ++m)
#pragma unroll
      for (int n = 0; n < 4; ++n)
        ac[m][n] = __builtin_amdgcn_mfma_f32_16x16x32_bf16(af[m], bfv[n], ac[m][n], 0, 0, 0);
  }

  const float* cdp = cumdecb + (size_t)bid * 128;
#pragma unroll
  for (int m = 0; m < 2; ++m) {
    int trow = tR0 + m * 16 + rb;
    float cd[4];
#pragma unroll
    for (int j = 0; j < 4; ++j) cd[j] = cdp[trow + j];
#pragma unroll
    for (int n = 0; n < 4; ++n) {
      int pc = n * 16 + fr;
      __hip_bfloat16* yp = y + ((size_t)b * LSEQ + t0 + trow) * DI + h * HD + pc;
#pragma unroll
      for (int j = 0; j < 4; ++j) {
        float old = __bfloat162float(yp[(size_t)j * DI]);
        yp[(size_t)j * DI] = __float2bfloat16(old + cd[j] * ac[m][n][j]);
      }
    }
  }
}

// ---------------- gating + RMS norm -> bf16 (8 cols/thread) ----------------

__global__ __launch_bounds__(256)
void gate_rms_kernel(const __hip_bfloat16* __restrict__ y, const __hip_bfloat16* __restrict__ zxb,
                     const float* __restrict__ nw, __hip_bfloat16* __restrict__ g) {
  int row = blockIdx.x;
  int t = threadIdx.x;
  int c0 = t * 8;
  const __hip_bfloat16* yr = y + (size_t)row * DI + c0;
  const __hip_bfloat16* zr = zxb + (size_t)row * NPAD + c0;
  ushort4 y0 = *reinterpret_cast<const ushort4*>(yr);
  ushort4 y1 = *reinterpret_cast<const ushort4*>(yr + 4);
  ushort4 z0 = *reinterpret_cast<const ushort4*>(zr);
  ushort4 z1 = *reinterpret_cast<const ushort4*>(zr + 4);
  float zf[8] = {bf2f(z0.x), bf2f(z0.y), bf2f(z0.z), bf2f(z0.w),
                 bf2f(z1.x), bf2f(z1.y), bf2f(z1.z), bf2f(z1.w)};
  float yf[8] = {bf2f(y0.x), bf2f(y0.y), bf2f(y0.z), bf2f(y0.w),
                 bf2f(y1.x), bf2f(y1.y), bf2f(y1.z), bf2f(y1.w)};
  float v[8];
  float ss = 0.f;
#pragma unroll
  for (int j = 0; j < 8; ++j) {
    float z = zf[j];
    float vv = yf[j] * (z / (1.f + expf(-z)));
    v[j] = vv;
    ss += vv * vv;
  }
#pragma unroll
  for (int off = 32; off; off >>= 1) ss += __shfl_down(ss, off);
  __shared__ float red[4];
  if ((t & 63) == 0) red[t >> 6] = ss;
  __syncthreads();
  float tot = red[0] + red[1] + red[2] + red[3];
  float rstd = rsqrtf(tot * (1.f / DI) + EPSV);
  float4 na = *reinterpret_cast<const float4*>(nw + c0);
  float4 nb = *reinterpret_cast<const float4*>(nw + c0 + 4);
  ushort4 o0 = pack4(v[0] * rstd * na.x, v[1] * rstd * na.y,
                     v[2] * rstd * na.z, v[3] * rstd * na.w);
  ushort4 o1v = pack4(v[4] * rstd * nb.x, v[5] * rstd * nb.y,
                      v[6] * rstd * nb.z, v[7] * rstd * nb.w);
  ushort4* gp = reinterpret_cast<ushort4*>(g + (size_t)row * DI + c0);
  gp[0] = o0;
  gp[1] = o1v;
}

// ---------------- final: sum 4 bf16 split-K partials, RMS, + residual ----------------

__global__ __launch_bounds__(256)
void final_rms_add(const __hip_bfloat16* __restrict__ o1p, const float* __restrict__ x,
                   float* __restrict__ out) {
  int row = blockIdx.x;
  int t = threadIdx.x;
  int c0 = t * 4;
  size_t off = (size_t)row * DMODEL + c0;
  float4 o = {0.f, 0.f, 0.f, 0.f};
#pragma unroll
  for (int s = 0; s < 4; ++s) {
    ushort4 p = *reinterpret_cast<const ushort4*>(o1p + (size_t)s * 4194304 + off);
    o.x += bf2f(p.x); o.y += bf2f(p.y); o.z += bf2f(p.z); o.w += bf2f(p.w);
  }
  float ss = o.x * o.x + o.y * o.y + o.z * o.z + o.w * o.w;
#pragma unroll
  for (int off2 = 32; off2; off2 >>= 1) ss += __shfl_down(ss, off2);
  __shared__ float red[4];
  if ((t & 63) == 0) red[t >> 6] = ss;
  __syncthreads();
  float tot = red[0] + red[1] + red[2] + red[3];
  float rstd = rsqrtf(tot * (1.f / DMODEL) + EPSV);
  float4 xv = *reinterpret_cast<const float4*>(x + off);
  float4 r;
  r.x = o.x * rstd + xv.x;
  r.y = o.y * rstd + xv.y;
  r.z = o.z * rstd + xv.z;
  r.w = o.w * rstd + xv.w;
  *reinterpret_cast<float4*>(out + off) = r;
}

// ---------------- launch ----------------

extern "C" void kernel_launch(void* const* d_in, const int* in_sizes, int n_in,
                              void* d_out, int out_size, void* d_ws, size_t ws_size,
                              hipStream_t stream) {
  const float* x       = (const float*)d_in[0];
  const float* W_in    = (const float*)d_in[1];
  const float* conv_w  = (const float*)d_in[2];
  const float* conv_b  = (const float*)d_in[3];
  const float* dt_bias = (const float*)d_in[4];
  const float* A_log   = (const float*)d_in[5];
  const float* Dp      = (const float*)d_in[6];
  const float* norm_w  = (const float*)d_in[7];
  const float* W_out   = (const float*)d_in[8];
  float* out = (float*)d_out;

  float* zxF  = (float*)d_ws;                               // slot holds zxb bf16 4096x4480
  __hip_bfloat16* zxb = (__hip_bfloat16*)zxF;
  __hip_bfloat16* o1p = zxb;   // overlay: zxb dead after gate_rms; 4 x 4096x1024 bf16
  float* xbcF = zxF + (size_t)18350080;                     // slot: 9437184 f32
  __hip_bfloat16* xbc = (__hip_bfloat16*)xbcF;              // 4096 x 2304 bf16
  float* ybufF = xbcF + (size_t)9437184;                    // slot: 8388608 f32
  __hip_bfloat16* ybuf = (__hip_bfloat16*)ybufF;            // 4096 x 2048 bf16
  float* dtraw = ybufF + (size_t)8388608;                   // 131072 (4096 x 32 f32)
  float* cumdecb = dtraw + (size_t)131072;                  // 131072 (1024 x 128)
  __hip_bfloat16* xbf   = (__hip_bfloat16*)(cumdecb + 131072); // 4096x1024
  __hip_bfloat16* wtin  = xbf + (size_t)4194304;               // 4480x1024
  __hip_bfloat16* wtout = wtin + (size_t)4587520;              // 1024x2048
  float* pbuf = (float*)(wtout + (size_t)2097152);             // 1024
  float* csb  = pbuf + 1024;                                   // 1024 x 128
  float* dtc  = csb + (size_t)131072;                          // 1024 x 128
  float* swb  = dtc + (size_t)131072;                          // 1024 x 128
  __hip_bfloat16* sbuf = xbf;  // overlay: xbf/wtin dead after GEMM1
  __hip_bfloat16* gbf = xbf;   // overlay: sbuf dead after ssd_mfma_corr

  prep_kernel<<<10624, 256, 0, stream>>>(x, xbf, W_in, wtin, W_out, wtout);

  // GEMM1: grid 256 — each block: 256^2 main tile with the 128x48 remainder tile
  // FUSED into the same K-pipeline (+dt side-channel). No tail phase.
  gemm256_bt<0><<<256, 512, 0, stream>>>(xbf, wtin, zxb, dtraw, 1024);

  conv_stats_kernel<<<832, 256, 0, stream>>>(zxb, conv_w, conv_b, xbc,
                                             dtraw, dt_bias, A_log,
                                             csb, dtc, swb, cumdecb, pbuf);

  ssd_mfma_local<<<1024, 256, 0, stream>>>(xbc, csb, dtc, swb, A_log, Dp, ybuf, sbuf);
  ssd_prop_kernel<<<2048, 256, 0, stream>>>(sbuf, pbuf);
  ssd_mfma_corr<<<960, 256, 0, stream>>>(xbc, sbuf, cumdecb, ybuf);

  gate_rms_kernel<<<4096, 256, 0, stream>>>(ybuf, zxb, norm_w, gbf);

  // GEMM2: 256^2 split-K=4 (grid 256 = 1/CU), bf16 partials into dead zxb slot.
  gemm256_bt<1><<<256, 512, 0, stream>>>(gbf, wtout, o1p, nullptr, 2048);

  final_rms_add<<<4096, 256, 0, stream>>>(o1p, x, out);
}

// Round 29
// 168.465 us; speedup vs baseline: 1.0591x; 1.0269x over previous
//
#include <hip/hip_runtime.h>
#include <hip/hip_bf16.h>

#define DMODEL 1024
#define DI     2048
#define DSTATE 128
#define NH     32
#define HD     64
#define CONVD  2304
#define LSEQ   2048
#define BATCH  2
#define DPROJ  4384
#define NPAD   4480      // zxb column stride
#define EPSV   1e-5f
#define QCH    128
#define NCH    16

#define AS1 __attribute__((address_space(1)))
#define AS3 __attribute__((address_space(3)))

typedef __attribute__((ext_vector_type(8))) short bf16x8;
typedef __attribute__((ext_vector_type(4))) float f32x4;

union U4 { ushort4 u; __hip_bfloat16 h[4]; };

__device__ __forceinline__ float bf2f(unsigned short u) {
  union { unsigned int i; float f; } c; c.i = ((unsigned)u) << 16; return c.f;
}
__device__ __forceinline__ ushort4 pack4(float x0, float x1, float x2, float x3) {
  U4 p;
  p.h[0] = __float2bfloat16(x0); p.h[1] = __float2bfloat16(x1);
  p.h[2] = __float2bfloat16(x2); p.h[3] = __float2bfloat16(x3);
  return p.u;
}

// ---- swizzled LDS helpers: [rows][128] bf16 tiles (256B rows), byte ^= (row&7)<<4 ----
__device__ __forceinline__ bf16x8 ldsfrag(const __hip_bfloat16* base, int row, int ke) {
  int byte = row * 256 + ke * 2;
  byte ^= (row & 7) << 4;
  return *reinterpret_cast<const bf16x8*>(reinterpret_cast<const char*>(base) + byte);
}
__device__ __forceinline__ void ldswr4(__hip_bfloat16* base, int row, int col, ushort4 v) {
  int byte = row * 256 + col * 2;
  byte ^= (row & 7) << 4;
  *reinterpret_cast<ushort4*>(reinterpret_cast<char*>(base) + byte) = v;
}
__device__ __forceinline__ ushort4 ldsrd4(const __hip_bfloat16* base, int row, int col) {
  int byte = row * 256 + col * 2;
  byte ^= (row & 7) << 4;
  return *reinterpret_cast<const ushort4*>(reinterpret_cast<const char*>(base) + byte);
}
__device__ __forceinline__ void ldswr8(__hip_bfloat16* base, int row, int colElem,
                                       unsigned lo, unsigned hi) {
  int byte = row * 256 + colElem * 2;
  byte ^= (row & 7) << 4;
  uint2 v; v.x = lo; v.y = hi;
  *reinterpret_cast<uint2*>(reinterpret_cast<char*>(base) + byte) = v;
}
// ---- swizzled helper for [rows][32] bf16 tiles (64B rows): chunk g ^= (row>>1)&3 ----
__device__ __forceinline__ bf16x8 frag32(const __hip_bfloat16* base, int row, int g) {
  int byte = row * 64 + (((g ^ (row >> 1)) & 3) << 4);
  return *reinterpret_cast<const bf16x8*>(reinterpret_cast<const char*>(base) + byte);
}

// ---- in-register 4x4 u16 transpose across a quad (lanes ql=0..3) ----
__device__ __forceinline__ void quadtr(unsigned a01, unsigned a23, int ql,
                                       unsigned& w01, unsigned& w23) {
  unsigned y01 = __shfl_xor((int)a01, 1), y23 = __shfl_xor((int)a23, 1);
  unsigned c01 = (ql & 1) ? ((y01 >> 16) | (a01 & 0xFFFF0000u))
                          : ((a01 & 0xFFFFu) | (y01 << 16));
  unsigned c23 = (ql & 1) ? ((y23 >> 16) | (a23 & 0xFFFF0000u))
                          : ((a23 & 0xFFFFu) | (y23 << 16));
  unsigned d01 = __shfl_xor((int)c01, 2), d23 = __shfl_xor((int)c23, 2);
  w01 = (ql & 2) ? d23 : c01;
  w23 = (ql & 2) ? c23 : d01;
}

// ---------------- merged prep: x->bf16 + W_in^T + W_out^T in one launch ----------------

__global__ __launch_bounds__(256)
void prep_kernel(const float* __restrict__ x, __hip_bfloat16* __restrict__ xbf,
                 const float* __restrict__ W_in, __hip_bfloat16* __restrict__ wtin,
                 const float* __restrict__ W_out, __hip_bfloat16* __restrict__ wtout) {
  __shared__ float tile[32][33];
  const int b = blockIdx.x, tid = threadIdx.x;
  if (b < 4096) {
    int i = b * 256 + tid;
    float4 v = reinterpret_cast<const float4*>(x)[i];
    reinterpret_cast<ushort4*>(xbf)[i] = pack4(v.x, v.y, v.z, v.w);
    return;
  }
  const float* in;
  __hip_bfloat16* outp;
  int R, C, Cpad, n0, k0;
  if (b < 4096 + 4480) {
    int t = b - 4096;
    in = W_in; outp = wtin; R = 1024; C = 4384; Cpad = 4480;
    n0 = (t % 140) * 32; k0 = (t / 140) * 32;
  } else {
    int t = b - 8576;
    in = W_out; outp = wtout; R = 2048; C = 1024; Cpad = 1024;
    n0 = (t % 32) * 32; k0 = (t / 32) * 32;
  }
  int tx = tid & 31, ty = tid >> 5;
#pragma unroll
  for (int j = 0; j < 32; j += 8) {
    int k = k0 + ty + j, n = n0 + tx;
    tile[ty + j][tx] = (n < C) ? in[(size_t)k * C + n] : 0.f;
  }
  __syncthreads();
#pragma unroll
  for (int j = 0; j < 32; j += 8) {
    int n = n0 + ty + j, k = k0 + tx;
    if (n < Cpad) outp[(size_t)n * R + k] = __float2bfloat16(tile[tx][ty + j]);
  }
}

// ---------------- GEMM1 256x256: BK=32, 4-buffer depth-2 counted-vmcnt ----------------
// grid 256; block (p=bm/256, q=bn/256) computes its 256^2 main tile AND the remainder
// tile {rows p*256+(q&1)*128..+128, cols 4096+(q>>1)*48..+48} FUSED into the same
// K-pipeline (B2 staged by waves 0-2). +dt side-channel.

__global__ __launch_bounds__(512, 2)
void gemm256_bt(const __hip_bfloat16* __restrict__ A,
                const __hip_bfloat16* __restrict__ Bt,
                __hip_bfloat16* __restrict__ Cout,
                float* __restrict__ dtraw, int K) {
  __shared__ __hip_bfloat16 smA[4][256 * 32];
  __shared__ __hip_bfloat16 smB[4][256 * 32];
  __shared__ __hip_bfloat16 smB2[4][48 * 32];   // remainder B tile (12 KB)

  const int xcd = blockIdx.x & 7;
  const int i = blockIdx.x >> 3;            // 0..31
  const int bm = (xcd * 2 + (i & 1)) * 256; // XCD owns 2 M-panels, m-fastest
  const int bn = (i >> 1) * 256;
  const int q2 = i >> 1;                    // 0..15

  const int tid = threadIdx.x;
  const int w = tid >> 6, lane = tid & 63;
  const int wm = w >> 2, wn = w & 3;
  const int fr = lane & 15, g = lane >> 4;
  const int srow = tid >> 2;                       // 0..127
  const int sc = (((tid & 3) ^ ((srow >> 1) & 3)) << 3);  // inverse-swizzled col
  const int rbase = (q2 & 1) * 128;                // remainder rows within block A tile

  f32x4 acc[8][4];
#pragma unroll
  for (int m = 0; m < 8; ++m)
#pragma unroll
    for (int n = 0; n < 4; ++n) acc[m][n] = (f32x4){0.f, 0.f, 0.f, 0.f};
  f32x4 acc2[3];
#pragma unroll
  for (int n = 0; n < 3; ++n) acc2[n] = (f32x4){0.f, 0.f, 0.f, 0.f};

  const __hip_bfloat16* aS = A + (size_t)(bm + srow) * K + sc;
  const __hip_bfloat16* bS = Bt + (size_t)(bn + srow) * K + sc;
  // remainder B rows (valid deref only for tid<192: srow<48)
  const __hip_bfloat16* bS2 = Bt + (size_t)(4096 + (q2 >> 1) * 48 + srow) * K + sc;
  const int dbase = w * 512;

  auto STAGE = [&](int buf, int kt) {
    const int k0 = kt << 5;
#pragma unroll
    for (int j = 0; j < 2; ++j) {
      __builtin_amdgcn_global_load_lds((const AS1 void*)(aS + (size_t)(j * 128) * K + k0),
                                       (AS3 void*)(&smA[buf][j * 4096 + dbase]), 16, 0, 0);
      __builtin_amdgcn_global_load_lds((const AS1 void*)(bS + (size_t)(j * 128) * K + k0),
                                       (AS3 void*)(&smB[buf][j * 4096 + dbase]), 16, 0, 0);
    }
    if (w < 3)
      __builtin_amdgcn_global_load_lds((const AS1 void*)(bS2 + k0),
                                       (AS3 void*)(&smB2[buf][dbase]), 16, 0, 0);
  };

  const int nt = K >> 5;
  STAGE(0, 0);
  STAGE(1, 1);
  for (int kt = 0; kt < nt; ++kt) {
    const int cur = kt & 3;
    if (kt + 2 < nt) {
      STAGE((kt + 2) & 3, kt + 2);
      if (w < 3) { asm volatile("s_waitcnt vmcnt(10)" ::: "memory"); }
      else       { asm volatile("s_waitcnt vmcnt(8)" ::: "memory"); }
    } else if (kt + 1 < nt) {
      if (w < 3) { asm volatile("s_waitcnt vmcnt(5)" ::: "memory"); }
      else       { asm volatile("s_waitcnt vmcnt(4)" ::: "memory"); }
    } else {
      asm volatile("s_waitcnt vmcnt(0)" ::: "memory");
    }
    __builtin_amdgcn_s_barrier();
    __builtin_amdgcn_s_setprio(1);
    bf16x8 af[8], bfv[4];
#pragma unroll
    for (int m = 0; m < 8; ++m)
      af[m] = frag32(&smA[cur][0], wm * 128 + m * 16 + fr, g);
#pragma unroll
    for (int n = 0; n < 4; ++n)
      bfv[n] = frag32(&smB[cur][0], wn * 64 + n * 16 + fr, g);
#pragma unroll
    for (int m = 0; m < 8; ++m)
#pragma unroll
      for (int n = 0; n < 4; ++n)
        acc[m][n] = __builtin_amdgcn_mfma_f32_16x16x32_bf16(af[m], bfv[n], acc[m][n], 0, 0, 0);
    {
      // fused remainder: wave w owns remainder rows rbase + w*16 .. +16
      bf16x8 a2 = frag32(&smA[cur][0], rbase + w * 16 + fr, g);
      bf16x8 b2[3];
#pragma unroll
      for (int n = 0; n < 3; ++n)
        b2[n] = frag32(&smB2[cur][0], n * 16 + fr, g);
#pragma unroll
      for (int n = 0; n < 3; ++n)
        acc2[n] = __builtin_amdgcn_mfma_f32_16x16x32_bf16(a2, b2[n], acc2[n], 0, 0, 0);
    }
    __builtin_amdgcn_s_setprio(0);
  }

  const int rb = g * 4;
#pragma unroll
  for (int m = 0; m < 8; ++m)
#pragma unroll
    for (int n = 0; n < 4; ++n) {
      int row = bm + wm * 128 + m * 16 + rb;
      int col = bn + wn * 64 + n * 16 + fr;
      __hip_bfloat16* cp = Cout + (size_t)row * NPAD + col;
#pragma unroll
      for (int j = 0; j < 4; ++j)
        cp[(size_t)j * NPAD] = __float2bfloat16(acc[m][n][j]);
    }

  // fused remainder epilogue: rows bm+rbase+w*16.., cols 4096+(q2>>1)*48..
  const int bn2 = 4096 + (q2 >> 1) * 48;
#pragma unroll
  for (int n = 0; n < 3; ++n) {
    int row = bm + rbase + w * 16 + rb;
    int col = bn2 + n * 16 + fr;
    __hip_bfloat16* cp = Cout + (size_t)row * NPAD + col;
#pragma unroll
    for (int j = 0; j < 4; ++j) {
      float v = acc2[n][j];
      cp[(size_t)j * NPAD] = __float2bfloat16(v);
      if (col >= DI + CONVD && col < DPROJ)
        dtraw[(size_t)(row + j) * NH + (col - (DI + CONVD))] = v;
    }
  }
}

// ---------------- GEMM2: 256x128 tile, split-K=2, BK=32 4-buffer depth-2 ----------------
// grid 256 = 2 splits x (16 M-panels x 8 N-panels). 8 waves as 4M x 2N, wave tile
// 64x64, acc[4][4]. Staging: A 2 loads/thread, B 1 load/thread (uniform 3) ->
// vmcnt 6/3/0. Partials: 2 x 4096x1024 bf16.

__global__ __launch_bounds__(512, 2)
void gemm2_bt(const __hip_bfloat16* __restrict__ A,
              const __hip_bfloat16* __restrict__ Bt,
              __hip_bfloat16* __restrict__ Cout) {
  __shared__ __hip_bfloat16 smA[4][256 * 32];   // 64 KB
  __shared__ __hip_bfloat16 smB[4][128 * 32];   // 32 KB
  const int K = 2048;

  const int bb = blockIdx.x;
  const int s = bb >> 7;                    // split 0/1
  const int t = bb & 127;
  const int xcd = t & 7;
  const int i = t >> 3;                     // 0..15
  const int bm = (xcd * 2 + (i & 1)) * 256;
  const int bn = (i >> 1) * 128;            // 0..7 -> 0..896
  const int kbase = s * 1024;

  const int tid = threadIdx.x;
  const int w = tid >> 6, lane = tid & 63;
  const int wm = w >> 1, wn = w & 1;        // 4M x 2N
  const int fr = lane & 15, g = lane >> 4;
  const int srow = tid >> 2;                // 0..127
  const int sc = (((tid & 3) ^ ((srow >> 1) & 3)) << 3);
  const int dbase = w * 512;

  f32x4 acc[4][4];
#pragma unroll
  for (int m = 0; m < 4; ++m)
#pragma unroll
    for (int n = 0; n < 4; ++n) acc[m][n] = (f32x4){0.f, 0.f, 0.f, 0.f};

  const __hip_bfloat16* aS = A + (size_t)(bm + srow) * K + kbase + sc;
  const __hip_bfloat16* bS = Bt + (size_t)(bn + srow) * K + kbase + sc;

  auto STAGE = [&](int buf, int kt) {
    const int k0 = kt << 5;
#pragma unroll
    for (int j = 0; j < 2; ++j)
      __builtin_amdgcn_global_load_lds((const AS1 void*)(aS + (size_t)(j * 128) * K + k0),
                                       (AS3 void*)(&smA[buf][j * 4096 + dbase]), 16, 0, 0);
    __builtin_amdgcn_global_load_lds((const AS1 void*)(bS + k0),
                                     (AS3 void*)(&smB[buf][dbase]), 16, 0, 0);
  };

  const int nt = 32;                        // Kp=1024 / 32
  STAGE(0, 0);
  STAGE(1, 1);
  for (int kt = 0; kt < nt; ++kt) {
    const int cur = kt & 3;
    if (kt + 2 < nt) {
      STAGE((kt + 2) & 3, kt + 2);
      asm volatile("s_waitcnt vmcnt(6)" ::: "memory");
    } else if (kt + 1 < nt) {
      asm volatile("s_waitcnt vmcnt(3)" ::: "memory");
    } else {
      asm volatile("s_waitcnt vmcnt(0)" ::: "memory");
    }
    __builtin_amdgcn_s_barrier();
    __builtin_amdgcn_s_setprio(1);
    bf16x8 af[4], bfv[4];
#pragma unroll
    for (int m = 0; m < 4; ++m)
      af[m] = frag32(&smA[cur][0], wm * 64 + m * 16 + fr, g);
#pragma unroll
    for (int n = 0; n < 4; ++n)
      bfv[n] = frag32(&smB[cur][0], wn * 64 + n * 16 + fr, g);
#pragma unroll
    for (int m = 0; m < 4; ++m)
#pragma unroll
      for (int n = 0; n < 4; ++n)
        acc[m][n] = __builtin_amdgcn_mfma_f32_16x16x32_bf16(af[m], bfv[n], acc[m][n], 0, 0, 0);
    __builtin_amdgcn_s_setprio(0);
  }

  const int rb = g * 4;
#pragma unroll
  for (int m = 0; m < 4; ++m)
#pragma unroll
    for (int n = 0; n < 4; ++n) {
      int row = bm + wm * 64 + m * 16 + rb;
      int col = bn + wn * 64 + n * 16 + fr;
      __hip_bfloat16* cp = Cout + (size_t)s * 4194304 + (size_t)row * DMODEL + col;
#pragma unroll
      for (int j = 0; j < 4; ++j)
        cp[(size_t)j * DMODEL] = __float2bfloat16(acc[m][n][j]);
    }
}

// ---------------- merged conv v3 + chunk_stats (independent, one launch) ----------------
// blocks [0,1152): conv 8 timesteps x 4 channels/thread; [1152,1408): chunk stats.

__global__ __launch_bounds__(256)
void conv_stats_kernel(const __hip_bfloat16* __restrict__ zxb,
                       const float* __restrict__ cw,
                       const float* __restrict__ cb,
                       __hip_bfloat16* __restrict__ xbc,
                       const float* __restrict__ dtraw, const float* __restrict__ dt_bias,
                       const float* __restrict__ A_log,
                       float* __restrict__ csb, float* __restrict__ dtc,
                       float* __restrict__ swb, float* __restrict__ cumdecb,
                       float* __restrict__ pbuf) {
  if (blockIdx.x >= 1152) {
    // ---- chunk stats: one wave per (b,h,c) ----
    int w = threadIdx.x >> 6, lane = threadIdx.x & 63;
    int bid = (blockIdx.x - 1152) * 4 + w;  // 0..1023
    int c = bid & (NCH - 1);
    int h = (bid >> 4) & 31;
    int b = bid >> 9;
    int t0 = c * QCH;
    float a = expf(A_log[h]);
    float bias = dt_bias[h];
    const float* dtp = dtraw + ((size_t)b * LSEQ + t0) * NH + h;
    float r0 = dtp[lane * NH] + bias;
    float r1 = dtp[(64 + lane) * NH] + bias;
    float v0 = (r0 > 20.f) ? r0 : log1pf(expf(r0));
    float v1 = (r1 > 20.f) ? r1 : log1pf(expf(r1));
    float s0 = v0;
#pragma unroll
    for (int off = 1; off < 64; off <<= 1) {
      float tv = __shfl_up(s0, off);
      if (lane >= off) s0 += tv;
    }
    float T0 = __shfl(s0, 63);
    float s1 = v1;
#pragma unroll
    for (int off = 1; off < 64; off <<= 1) {
      float tv = __shfl_up(s1, off);
      if (lane >= off) s1 += tv;
    }
    float cs1 = s1 + T0;
    float Tt = __shfl(s1, 63) + T0;
    size_t base = (size_t)bid * 128;
    csb[base + lane] = s0;        csb[base + 64 + lane] = cs1;
    dtc[base + lane] = v0;        dtc[base + 64 + lane] = v1;
    swb[base + lane] = v0 * expf(-a * (Tt - s0));
    swb[base + 64 + lane] = v1 * expf(-a * (Tt - cs1));
    cumdecb[base + lane] = expf(-a * s0);
    cumdecb[base + 64 + lane] = expf(-a * cs1);
    if (lane == 0) pbuf[bid] = expf(-a * Tt);
    return;
  }
  // ---- conv: 8 timesteps x 4 channels per thread ----
  int idx = blockIdx.x * 256 + threadIdx.x;
  int c4 = idx % (CONVD / 4);
  int bl8 = idx / (CONVD / 4);
  int l0 = (bl8 % (LSEQ / 8)) * 8;
  int b = bl8 / (LSEQ / 8);
  int c0 = c4 * 4;
  const __hip_bfloat16* src = zxb + (size_t)b * LSEQ * NPAD + DI + c0;

  float wv[4][4];
#pragma unroll
  for (int j = 0; j < 4; ++j)
    *reinterpret_cast<float4*>(wv[j]) = *reinterpret_cast<const float4*>(cw + (c0 + j) * 4);
  float bias[4];
  *reinterpret_cast<float4*>(bias) = *reinterpret_cast<const float4*>(cb + c0);

  float hist[11][4];
#pragma unroll
  for (int r = 0; r < 11; ++r) {
    int row = l0 - 3 + r;
    if (row >= 0) {
      ushort4 v = *reinterpret_cast<const ushort4*>(src + (size_t)row * NPAD);
      hist[r][0] = bf2f(v.x); hist[r][1] = bf2f(v.y);
      hist[r][2] = bf2f(v.z); hist[r][3] = bf2f(v.w);
    } else {
#pragma unroll
      for (int j = 0; j < 4; ++j) hist[r][j] = 0.f;
    }
  }

#pragma unroll
  for (int t = 0; t < 8; ++t) {
    float acc[4];
#pragma unroll
    for (int j = 0; j < 4; ++j) {
      float a = bias[j];
      a = fmaf(wv[j][0], hist[t + 0][j], a);
      a = fmaf(wv[j][1], hist[t + 1][j], a);
      a = fmaf(wv[j][2], hist[t + 2][j], a);
      a = fmaf(wv[j][3], hist[t + 3][j], a);
      acc[j] = a / (1.f + expf(-a));
    }
    *reinterpret_cast<ushort4*>(xbc + ((size_t)b * LSEQ + l0 + t) * CONVD + c0) =
        pack4(acc[0], acc[1], acc[2], acc[3]);
  }
}

// ---------------- SSD pass 1: per-chunk MFMA ----------------
// Bw^T built from LDS (T_B) before P overwrites it; one extra barrier.

__global__ __launch_bounds__(256, 2)
void ssd_mfma_local(const __hip_bfloat16* __restrict__ bxc,
                    const float* __restrict__ csb, const float* __restrict__ dtc,
                    const float* __restrict__ swb,
                    const float* __restrict__ A_log, const float* __restrict__ Dparm,
                    __hip_bfloat16* __restrict__ y, __hip_bfloat16* __restrict__ sbuf) {
  __shared__ __hip_bfloat16 T_B[128 * 128];
  __shared__ __hip_bfloat16 T_C[128 * 128];
  __shared__ __hip_bfloat16 T_X[64 * 128];

  const int bid = blockIdx.x;
  const int c = bid & (NCH - 1);
  const int h = (bid >> 4) & 31;
  const int b = bid >> 9;
  const int tid = threadIdx.x;
  const int w = tid >> 6, lane = tid & 63;
  const int q = lane >> 2, ql = lane & 3;
  const int t0 = c * QCH;
  const __hip_bfloat16* xc = bxc + (size_t)b * LSEQ * CONVD;
  const float a = expf(A_log[h]);
  const float Dh = Dparm[h];

  {
    const int rsub = lane >> 4;
    const int ch = lane & 15;
#pragma unroll
    for (int j = 0; j < 8; ++j) {
      int row = w * 32 + j * 4 + rsub;
      int sc_ = ch ^ (row & 7);
      const __hip_bfloat16* pB = xc + (size_t)(t0 + row) * CONVD + DI + sc_ * 8;
      __builtin_amdgcn_global_load_lds((const AS1 void*)pB,
                                       (AS3 void*)(T_B + (w * 32 + j * 4) * 128), 16, 0, 0);
      __builtin_amdgcn_global_load_lds((const AS1 void*)(pB + DSTATE),
                                       (AS3 void*)(T_C + (w * 32 + j * 4) * 128), 16, 0, 0);
    }
  }
#pragma unroll
  for (int r = 0; r < 8; ++r) {
    int gidx = w * 128 + q * 8 + r;     // 0..511
    int tb = (gidx & 31) * 4;
    int pb = (gidx >> 5) * 4;
    int t = tb + ql;
    ushort4 xv = *reinterpret_cast<const ushort4*>(xc + (size_t)(t0 + t) * CONVD + h * HD + pb);
    unsigned a01 = (unsigned)xv.x | ((unsigned)xv.y << 16);
    unsigned a23 = (unsigned)xv.z | ((unsigned)xv.w << 16);
    unsigned w01, w23;
    quadtr(a01, a23, ql, w01, w23);
    ldswr8(T_X, pb + ql, tb, w01, w23);
  }
  __syncthreads();

  const int fr = lane & 15;
  const int fk = (lane >> 4) * 8;
  const int rb = (lane >> 4) * 4;

  // ---- phase 2: G^T[s][t] = sum_n B[s][n] C[t][n]; wave quadrant 64x64 ----
  const int sR0 = (w >> 1) * 64, tC0 = (w & 1) * 64;
  f32x4 g[4][4];
#pragma unroll
  for (int m = 0; m < 4; ++m)
#pragma unroll
    for (int n = 0; n < 4; ++n) g[m][n] = (f32x4){0.f, 0.f, 0.f, 0.f};
  for (int kk = 0; kk < 128; kk += 32) {
    bf16x8 af[4], bfv[4];
#pragma unroll
    for (int m = 0; m < 4; ++m) af[m] = ldsfrag(T_B, sR0 + m * 16 + fr, kk + fk);
#pragma unroll
    for (int n = 0; n < 4; ++n) bfv[n] = ldsfrag(T_C, tC0 + n * 16 + fr, kk + fk);
#pragma unroll
    for (int m = 0; m < 4; ++m)
#pragma unroll
      for (int n = 0; n < 4; ++n)
        g[m][n] = __builtin_amdgcn_mfma_f32_16x16x32_bf16(af[m], bfv[n], g[m][n], 0, 0, 0);
  }
  __syncthreads();  // all waves done reading T_B/T_C

  // ---- Bw^T build: read B from T_B (LDS), scale by w_t, quad-transpose -> T_C ----
  {
    const float* swp = swb + (size_t)bid * 128;
#pragma unroll
    for (int r = 0; r < 16; ++r) {
      int gidx = w * 256 + q * 16 + r;   // 0..1023
      int tb = (gidx & 31) * 4;
      int nb = (gidx >> 5) * 4;
      int t = tb + ql;
      ushort4 bv = ldsrd4(T_B, t, nb);
      float wt = swp[t];
      ushort4 sv = pack4(bf2f(bv.x) * wt, bf2f(bv.y) * wt, bf2f(bv.z) * wt, bf2f(bv.w) * wt);
      unsigned a01 = (unsigned)sv.x | ((unsigned)sv.y << 16);
      unsigned a23 = (unsigned)sv.z | ((unsigned)sv.w << 16);
      unsigned w01, w23;
      quadtr(a01, a23, ql, w01, w23);
      ldswr8(T_C, nb + ql, tb, w01, w23);
    }
  }
  __syncthreads();  // B reads of T_B done before P overwrites it

  // ---- mask L (+D diag) -> write P[t][s] into T_B ----
  {
    const float* csp = csb + (size_t)bid * 128;
    const float* dtp = dtc + (size_t)bid * 128;
#pragma unroll
    for (int m = 0; m < 4; ++m) {
      int sb0 = sR0 + m * 16 + rb;
      float cs_s[4], dt_s[4];
#pragma unroll
      for (int j = 0; j < 4; ++j) { cs_s[j] = csp[sb0 + j]; dt_s[j] = dtp[sb0 + j]; }
#pragma unroll
      for (int n = 0; n < 4; ++n) {
        int tt = tC0 + n * 16 + fr;
        float cst = csp[tt];
        float vv[4];
#pragma unroll
        for (int j = 0; j < 4; ++j) {
          int s = sb0 + j;
          float e = __expf(-a * (cst - cs_s[j])) * dt_s[j];
          float pv = (s <= tt) ? g[m][n][j] * e : 0.f;
          vv[j] = pv + ((s == tt) ? Dh : 0.f);
        }
        ldswr4(T_B, tt, sb0, pack4(vv[0], vv[1], vv[2], vv[3]));
      }
    }
  }
  __syncthreads();

  // ---- phase 3: Y[t][p] = sum_s P[t][s] X[s][p] -> bf16 ----
  {
    int tR0 = w * 32;
    f32x4 yac[2][4];
#pragma unroll
    for (int m = 0; m < 2; ++m)
#pragma unroll
      for (int n = 0; n < 4; ++n) yac[m][n] = (f32x4){0.f, 0.f, 0.f, 0.f};
    for (int kk = 0; kk < 128; kk += 32) {
      bf16x8 af[2], bfv[4];
#pragma unroll
      for (int m = 0; m < 2; ++m) af[m] = ldsfrag(T_B, tR0 + m * 16 + fr, kk + fk);
#pragma unroll
      for (int n = 0; n < 4; ++n) bfv[n] = ldsfrag(T_X, n * 16 + fr, kk + fk);
#pragma unroll
      for (int m = 0; m < 2; ++m)
#pragma unroll
        for (int n = 0; n < 4; ++n)
          yac[m][n] = __builtin_amdgcn_mfma_f32_16x16x32_bf16(af[m], bfv[n], yac[m][n], 0, 0, 0);
    }
#pragma unroll
    for (int m = 0; m < 2; ++m)
#pragma unroll
      for (int n = 0; n < 4; ++n) {
        int trow = tR0 + m * 16 + rb;
        int pc = n * 16 + fr;
        __hip_bfloat16* yp = y + ((size_t)b * LSEQ + t0 + trow) * DI + h * HD + pc;
#pragma unroll
        for (int j = 0; j < 4; ++j)
          yp[(size_t)j * DI] = __float2bfloat16(yac[m][n][j]);
      }
  }

  // ---- phase 4: S^T[p][n] = sum_t XT[p][t] BwT[n][t] -> sbuf[bid][p][n] ----
  {
    int pR0 = (w >> 1) * 32, nC0 = (w & 1) * 64;
    f32x4 sac[2][4];
#pragma unroll
    for (int m = 0; m < 2; ++m)
#pragma unroll
      for (int n = 0; n < 4; ++n) sac[m][n] = (f32x4){0.f, 0.f, 0.f, 0.f};
    for (int kk = 0; kk < 128; kk += 32) {
      bf16x8 af[2], bfv[4];
#pragma unroll
      for (int m = 0; m < 2; ++m) af[m] = ldsfrag(T_X, pR0 + m * 16 + fr, kk + fk);
#pragma unroll
      for (int n = 0; n < 4; ++n) bfv[n] = ldsfrag(T_C, nC0 + n * 16 + fr, kk + fk);
#pragma unroll
      for (int m = 0; m < 2; ++m)
#pragma unroll
        for (int n = 0; n < 4; ++n)
          sac[m][n] = __builtin_amdgcn_mfma_f32_16x16x32_bf16(af[m], bfv[n], sac[m][n], 0, 0, 0);
    }
    __hip_bfloat16* sg = sbuf + (size_t)bid * 8192;
#pragma unroll
    for (int m = 0; m < 2; ++m)
#pragma unroll
      for (int n = 0; n < 4; ++n) {
        int p = pR0 + m * 16 + rb;
        int nn = nC0 + n * 16 + fr;
#pragma unroll
        for (int j = 0; j < 4; ++j)
          sg[(size_t)(p + j) * 128 + nn] = __float2bfloat16(sac[m][n][j]);
      }
  }
}

// ---------------- SSD pass 2: propagate chunk states ----------------

__global__ void ssd_prop_kernel(__hip_bfloat16* __restrict__ sbuf,
                                const float* __restrict__ pbuf) {
  int idx = blockIdx.x * 256 + threadIdx.x;   // 64 * 8192
  int bh = idx >> 13;
  int e = idx & 8191;
  __hip_bfloat16* base = sbuf + (size_t)bh * NCH * 8192 + e;
  const float* pb = pbuf + bh * NCH;
  float hs = 0.f;
  for (int cc = 0; cc < NCH; ++cc) {
    float sc = __bfloat162float(base[(size_t)cc * 8192]);
    base[(size_t)cc * 8192] = __float2bfloat16(hs);
    hs = fmaf(hs, pb[cc], sc);
  }
}

// ---------------- SSD pass 3: Y += diag(cumdec) * C @ h_start (LDS-free) ----------------

__global__ __launch_bounds__(256, 4)
void ssd_mfma_corr(const __hip_bfloat16* __restrict__ bxc, const __hip_bfloat16* __restrict__ sbuf,
                   const float* __restrict__ cumdecb, __hip_bfloat16* __restrict__ y) {
  const int bid = (blockIdx.x / 15) * 16 + 1 + (blockIdx.x % 15);
  const int h = (bid >> 4) & 31;
  const int b = bid >> 9;
  const int tid = threadIdx.x;
  const int w = tid >> 6, lane = tid & 63;
  const int t0 = (bid & (NCH - 1)) * QCH;
  const __hip_bfloat16* xc = bxc + (size_t)b * LSEQ * CONVD;
  const __hip_bfloat16* hsb = sbuf + (size_t)bid * 8192;
  const int fr = lane & 15;
  const int fk = (lane >> 4) * 8;
  const int rb = (lane >> 4) * 4;
  const int tR0 = w * 32;

  f32x4 ac[2][4];
#pragma unroll
  for (int m = 0; m < 2; ++m)
#pragma unroll
    for (int n = 0; n < 4; ++n) ac[m][n] = (f32x4){0.f, 0.f, 0.f, 0.f};

#pragma unroll
  for (int kk = 0; kk < 128; kk += 32) {
    bf16x8 af[2], bfv[4];
#pragma unroll
    for (int m = 0; m < 2; ++m)
      af[m] = *reinterpret_cast<const bf16x8*>(
          xc + (size_t)(t0 + tR0 + m * 16 + fr) * CONVD + DI + DSTATE + kk + fk);
#pragma unroll
    for (int n = 0; n < 4; ++n)
      bfv[n] = *reinterpret_cast<const bf16x8*>(hsb + (size_t)(n * 16 + fr) * 128 + kk + fk);
#pragma unroll
    for (int m = 0; m < 2; ++m)
#pragma unroll
      for (int n = 0; n < 4; ++n)
        ac[m][n] = __builtin_amdgcn_mfma_f32_16x16x32_bf16(af[m], bfv[n], ac[m][n], 0, 0, 0);
  }

  const float* cdp = cumdecb + (size_t)bid * 128;
#pragma unroll
  for (int m = 0; m < 2; ++m) {
    int trow = tR0 + m * 16 + rb;
    float cd[4];
#pragma unroll
    for (int j = 0; j < 4; ++j) cd[j] = cdp[trow + j];
#pragma unroll
    for (int n = 0; n < 4; ++n) {
      int pc = n * 16 + fr;
      __hip_bfloat16* yp = y + ((size_t)b * LSEQ + t0 + trow) * DI + h * HD + pc;
#pragma unroll
      for (int j = 0; j < 4; ++j) {
        float old = __bfloat162float(yp[(size_t)j * DI]);
        yp[(size_t)j * DI] = __float2bfloat16(old + cd[j] * ac[m][n][j]);
      }
    }
  }
}

// ---------------- gating + RMS norm -> bf16 (8 cols/thread) ----------------

__global__ __launch_bounds__(256)
void gate_rms_kernel(const __hip_bfloat16* __restrict__ y, const __hip_bfloat16* __restrict__ zxb,
                     const float* __restrict__ nw, __hip_bfloat16* __restrict__ g) {
  int row = blockIdx.x;
  int t = threadIdx.x;
  int c0 = t * 8;
  const __hip_bfloat16* yr = y + (size_t)row * DI + c0;
  const __hip_bfloat16* zr = zxb + (size_t)row * NPAD + c0;
  ushort4 y0 = *reinterpret_cast<const ushort4*>(yr);
  ushort4 y1 = *reinterpret_cast<const ushort4*>(yr + 4);
  ushort4 z0 = *reinterpret_cast<const ushort4*>(zr);
  ushort4 z1 = *reinterpret_cast<const ushort4*>(zr + 4);
  float zf[8] = {bf2f(z0.x), bf2f(z0.y), bf2f(z0.z), bf2f(z0.w),
                 bf2f(z1.x), bf2f(z1.y), bf2f(z1.z), bf2f(z1.w)};
  float yf[8] = {bf2f(y0.x), bf2f(y0.y), bf2f(y0.z), bf2f(y0.w),
                 bf2f(y1.x), bf2f(y1.y), bf2f(y1.z), bf2f(y1.w)};
  float v[8];
  float ss = 0.f;
#pragma unroll
  for (int j = 0; j < 8; ++j) {
    float z = zf[j];
    float vv = yf[j] * (z / (1.f + expf(-z)));
    v[j] = vv;
    ss += vv * vv;
  }
#pragma unroll
  for (int off = 32; off; off >>= 1) ss += __shfl_down(ss, off);
  __shared__ float red[4];
  if ((t & 63) == 0) red[t >> 6] = ss;
  __syncthreads();
  float tot = red[0] + red[1] + red[2] + red[3];
  float rstd = rsqrtf(tot * (1.f / DI) + EPSV);
  float4 na = *reinterpret_cast<const float4*>(nw + c0);
  float4 nb = *reinterpret_cast<const float4*>(nw + c0 + 4);
  ushort4 o0 = pack4(v[0] * rstd * na.x, v[1] * rstd * na.y,
                     v[2] * rstd * na.z, v[3] * rstd * na.w);
  ushort4 o1v = pack4(v[4] * rstd * nb.x, v[5] * rstd * nb.y,
                      v[6] * rstd * nb.z, v[7] * rstd * nb.w);
  ushort4* gp = reinterpret_cast<ushort4*>(g + (size_t)row * DI + c0);
  gp[0] = o0;
  gp[1] = o1v;
}

// ---------------- final: sum 2 bf16 split-K partials, RMS, + residual ----------------

__global__ __launch_bounds__(256)
void final_rms_add(const __hip_bfloat16* __restrict__ o1p, const float* __restrict__ x,
                   float* __restrict__ out) {
  int row = blockIdx.x;
  int t = threadIdx.x;
  int c0 = t * 4;
  size_t off = (size_t)row * DMODEL + c0;
  float4 o = {0.f, 0.f, 0.f, 0.f};
#pragma unroll
  for (int s = 0; s < 2; ++s) {
    ushort4 p = *reinterpret_cast<const ushort4*>(o1p + (size_t)s * 4194304 + off);
    o.x += bf2f(p.x); o.y += bf2f(p.y); o.z += bf2f(p.z); o.w += bf2f(p.w);
  }
  float ss = o.x * o.x + o.y * o.y + o.z * o.z + o.w * o.w;
#pragma unroll
  for (int off2 = 32; off2; off2 >>= 1) ss += __shfl_down(ss, off2);
  __shared__ float red[4];
  if ((t & 63) == 0) red[t >> 6] = ss;
  __syncthreads();
  float tot = red[0] + red[1] + red[2] + red[3];
  float rstd = rsqrtf(tot * (1.f / DMODEL) + EPSV);
  float4 xv = *reinterpret_cast<const float4*>(x + off);
  float4 r;
  r.x = o.x * rstd + xv.x;
  r.y = o.y * rstd + xv.y;
  r.z = o.z * rstd + xv.z;
  r.w = o.w * rstd + xv.w;
  *reinterpret_cast<float4*>(out + off) = r;
}

// ---------------- launch ----------------

extern "C" void kernel_launch(void* const* d_in, const int* in_sizes, int n_in,
                              void* d_out, int out_size, void* d_ws, size_t ws_size,
                              hipStream_t stream) {
  const float* x       = (const float*)d_in[0];
  const float* W_in    = (const float*)d_in[1];
  const float* conv_w  = (const float*)d_in[2];
  const float* conv_b  = (const float*)d_in[3];
  const float* dt_bias = (const float*)d_in[4];
  const float* A_log   = (const float*)d_in[5];
  const float* Dp      = (const float*)d_in[6];
  const float* norm_w  = (const float*)d_in[7];
  const float* W_out   = (const float*)d_in[8];
  float* out = (float*)d_out;

  float* zxF  = (float*)d_ws;                               // slot holds zxb bf16 4096x4480
  __hip_bfloat16* zxb = (__hip_bfloat16*)zxF;
  __hip_bfloat16* o1p = zxb;   // overlay: zxb dead after gate_rms; 2 x 4096x1024 bf16
  float* xbcF = zxF + (size_t)18350080;                     // slot: 9437184 f32
  __hip_bfloat16* xbc = (__hip_bfloat16*)xbcF;              // 4096 x 2304 bf16
  float* ybufF = xbcF + (size_t)9437184;                    // slot: 8388608 f32
  __hip_bfloat16* ybuf = (__hip_bfloat16*)ybufF;            // 4096 x 2048 bf16
  float* dtraw = ybufF + (size_t)8388608;                   // 131072 (4096 x 32 f32)
  float* cumdecb = dtraw + (size_t)131072;                  // 131072 (1024 x 128)
  __hip_bfloat16* xbf   = (__hip_bfloat16*)(cumdecb + 131072); // 4096x1024
  __hip_bfloat16* wtin  = xbf + (size_t)4194304;               // 4480x1024
  __hip_bfloat16* wtout = wtin + (size_t)4587520;              // 1024x2048
  float* pbuf = (float*)(wtout + (size_t)2097152);             // 1024
  float* csb  = pbuf + 1024;                                   // 1024 x 128
  float* dtc  = csb + (size_t)131072;                          // 1024 x 128
  float* swb  = dtc + (size_t)131072;                          // 1024 x 128
  __hip_bfloat16* sbuf = xbf;  // overlay: xbf/wtin dead after GEMM1
  __hip_bfloat16* gbf = xbf;   // overlay: sbuf dead after ssd_mfma_corr

  prep_kernel<<<10624, 256, 0, stream>>>(x, xbf, W_in, wtin, W_out, wtout);

  // GEMM1: grid 256 — each block: 256^2 main tile with the 128x48 remainder tile
  // FUSED into the same K-pipeline (+dt side-channel). No tail phase.
  gemm256_bt<<<256, 512, 0, stream>>>(xbf, wtin, zxb, dtraw, 1024);

  conv_stats_kernel<<<1408, 256, 0, stream>>>(zxb, conv_w, conv_b, xbc,
                                              dtraw, dt_bias, A_log,
                                              csb, dtc, swb, cumdecb, pbuf);

  ssd_mfma_local<<<1024, 256, 0, stream>>>(xbc, csb, dtc, swb, A_log, Dp, ybuf, sbuf);
  ssd_prop_kernel<<<2048, 256, 0, stream>>>(sbuf, pbuf);
  ssd_mfma_corr<<<960, 256, 0, stream>>>(xbc, sbuf, cumdecb, ybuf);

  gate_rms_kernel<<<4096, 256, 0, stream>>>(ybuf, zxb, norm_w, gbf);

  // GEMM2: 256x128 tile, split-K=2 (grid 256 = 1/CU), 32 K-steps, bf16 partials.
  gemm2_bt<<<256, 512, 0, stream>>>(gbf, wtout, o1p);

  final_rms_add<<<4096, 256, 0, stream>>>(o1p, x, out);
}